// Round 6
// baseline (337.780 us; speedup 1.0000x reference)
//
#include <hip/hip_runtime.h>
#include <math.h>

// ---------------------------------------------------------------------------
// DCN_Align on MI355X. Convs AND deformable conv on MFMA bf16 (16x16x32).
// Conv: per tap, D[cout][pix] += W_t[cout][cin] * X_t[cin][pix]; NHWC bf16.
// A-frags loaded per-tap from global (L1-hot; no VGPR cache); B double-
// buffered across taps; om head split into 4 cout-chunks via blockIdx.z.
// DCN: lane l samples pixel (l&15), group (l>>4) -> B-fragment directly.
// ---------------------------------------------------------------------------

#define BDIM 256

typedef __attribute__((ext_vector_type(8))) short short8v;
typedef __attribute__((ext_vector_type(4))) float f32x4;

__device__ __forceinline__ unsigned short f2bf(float f) {
    unsigned u = __builtin_bit_cast(unsigned, f);
    u = (u + 0x7FFF + ((u >> 16) & 1)) >> 16;   // round-to-nearest-even
    return (unsigned short)u;
}
__device__ __forceinline__ float bf2f(unsigned short h) {
    unsigned u = ((unsigned)h) << 16;
    return __builtin_bit_cast(float, u);
}

// ---------------------------------------------------------------------------
// MFMA conv: wave handles NT tiles of 16 consecutive x-pixels in one row.
// B-frag: lane l -> pixel (l&15), channels (l>>4)*8+j (16B NHWC load).
// A-frag: lane l -> cout coutBase+h*16+(l&15), channels (l>>4)*8+j.
// C/D: col(pixel)=lane&15, row(cout)=(lane>>4)*4+reg  [verified in-round].
// blockIdx.z selects a 16*NHALF cout chunk (A layout stride nhTot halves).
template<int NPASS, int NHALF, int NT, int STRIDE, bool LRELU>
__global__ __launch_bounds__(BDIM, 4)
void convm_k(const short* __restrict__ in0, const short* __restrict__ in1,
             const short* __restrict__ wf,   // [pass][tap][nhTot][lane][8] bf16
             const float* __restrict__ bias,
             short* __restrict__ out,        // NHWC bf16, channel stride OCS
             int Hin, int Win, int Hout, int Wout, int OCS, int coutTot,
             int nhTot)
{
    const int lane = threadIdx.x & 63;
    const int wid  = blockIdx.x * 4 + (threadIdx.x >> 6);
    const int segs = Wout / (16 * NT);
    const int b  = wid / (Hout * segs);
    int r = wid - b * (Hout * segs);
    const int oy = r / segs;
    const int x0 = (r - oy * segs) * (16 * NT);
    const int lp = lane & 15;
    const int g  = lane >> 4;
    const int hBase = blockIdx.z * NHALF;
    const int coutBase = blockIdx.z * NHALF * 16;

    // precomputed tap offsets + masks
    int rowOff[3]; bool rowOk[3];
#pragma unroll
    for (int ty = 0; ty < 3; ++ty) {
        const int iy = oy * STRIDE + ty - 1;
        rowOk[ty] = (unsigned)iy < (unsigned)Hin;
        rowOff[ty] = min(max(iy, 0), Hin - 1) * Win;
    }
    int colOff[3][NT]; bool colOk[3][NT];
#pragma unroll
    for (int tx = 0; tx < 3; ++tx)
#pragma unroll
        for (int nt = 0; nt < NT; ++nt) {
            const int ix = (x0 + nt * 16 + lp) * STRIDE + tx - 1;
            colOk[tx][nt] = (unsigned)ix < (unsigned)Win;
            colOff[tx][nt] = min(max(ix, 0), Win - 1) * 32 + g * 8;
        }

    f32x4 acc[NT][NHALF];
#pragma unroll
    for (int nt = 0; nt < NT; ++nt)
#pragma unroll
        for (int h = 0; h < NHALF; ++h)
            acc[nt][h] = (f32x4){0.f, 0.f, 0.f, 0.f};

    const size_t inPlane = (size_t)Hin * Win * 32;
    const short8v zero = {};

#pragma unroll
    for (int pass = 0; pass < NPASS; ++pass) {
        const short* inp = (pass == 0 ? in0 : in1) + (size_t)b * inPlane;

        short8v bcur[NT];
#pragma unroll
        for (int nt = 0; nt < NT; ++nt) {
            short8v v = *(const short8v*)(inp + (size_t)rowOff[0] * 32 + colOff[0][nt]);
            bcur[nt] = (rowOk[0] & colOk[0][nt]) ? v : zero;
        }

#pragma unroll
        for (int t = 0; t < 9; ++t) {
            short8v bnxt[NT];
            if (t < 8) {
                const int ty = (t + 1) / 3, tx = (t + 1) % 3;
#pragma unroll
                for (int nt = 0; nt < NT; ++nt) {
                    short8v v = *(const short8v*)(inp + (size_t)rowOff[ty] * 32 + colOff[tx][nt]);
                    bnxt[nt] = (rowOk[ty] & colOk[tx][nt]) ? v : zero;
                }
            }
#pragma unroll
            for (int h = 0; h < NHALF; ++h) {
                short8v av = *(const short8v*)(
                    wf + ((((size_t)pass * 9 + t) * nhTot + hBase + h) * 64 + lane) * 8);
#pragma unroll
                for (int nt = 0; nt < NT; ++nt)
                    acc[nt][h] = __builtin_amdgcn_mfma_f32_16x16x32_bf16(
                        av, bcur[nt], acc[nt][h], 0, 0, 0);
            }
            if (t < 8) {
#pragma unroll
                for (int nt = 0; nt < NT; ++nt) bcur[nt] = bnxt[nt];
            }
        }
    }

    const size_t outBase = ((size_t)b * Hout + oy) * Wout;
#pragma unroll
    for (int nt = 0; nt < NT; ++nt) {
        const int p = x0 + nt * 16 + lp;
        short* op = out + (outBase + p) * OCS;
#pragma unroll
        for (int h = 0; h < NHALF; ++h) {
            const int co0 = coutBase + h * 16 + g * 4;
            ushort4 st;
#pragma unroll
            for (int j = 0; j < 4; ++j) {
                float v = acc[nt][h][j] + bias[min(co0 + j, coutTot - 1)];
                if (LRELU) v = (v >= 0.f) ? v : 0.1f * v;
                ((unsigned short*)&st)[j] = f2bf(v);
            }
            if (co0 < coutTot)
                *(ushort4*)(op + co0) = st;
        }
    }
}

// ---------------------------------------------------------------------------
// Weight prep: [O][I][3][3] fp32 -> fragment layout bf16 [pass][t][h][lane][8].
struct WPArgs {
    const float* src[11];
    int off[11];      // dst offset in shorts
    int npass[11], nhalf[11], O[11];
};

__global__ __launch_bounds__(BDIM)
void wprep_k(WPArgs a, short* __restrict__ wbase)
{
    const int z = blockIdx.z;
    const int n = a.npass[z] * 9 * a.nhalf[z] * 512;
    const int idx = blockIdx.x * BDIM + threadIdx.x;
    if (idx >= n) return;
    const int j = idx & 7;
    const int l = (idx >> 3) & 63;
    int r = idx >> 9;
    const int h = r % a.nhalf[z]; r /= a.nhalf[z];
    const int t = r % 9;
    const int pass = r / 9;
    const int I = a.npass[z] * 32;
    const int cout = h * 16 + (l & 15);
    const int cin  = pass * 32 + (l >> 4) * 8 + j;
    float v = (cout < a.O[z]) ? a.src[z][((size_t)cout * I + cin) * 9 + t] : 0.f;
    wbase[a.off[z] + idx] = (short)f2bf(v);
}

// dcn weights [32o][32i][3][3] -> [tap][half][lane][8] bf16 frags
__global__ __launch_bounds__(BDIM)
void wdp_k(const float* __restrict__ w, short* __restrict__ dst)
{
    const int idx = blockIdx.x * BDIM + threadIdx.x;
    if (idx >= 9 * 2 * 64 * 8) return;
    const int j = idx & 7;
    const int l = (idx >> 3) & 63;
    const int h = (idx >> 9) & 1;
    const int k = idx >> 10;
    const int cout = h * 16 + (l & 15);
    const int cin  = (l >> 4) * 8 + j;
    dst[idx] = (short)f2bf(w[((size_t)cout * 32 + cin) * 9 + k]);
}

// fea NCHW fp32 -> NHWC bf16 (two tensors in one launch via z)
__global__ __launch_bounds__(BDIM)
void cvtnhwc_k(const float* __restrict__ s0, const float* __restrict__ s1,
               short* __restrict__ d0, short* __restrict__ d1, int H, int W)
{
    const float* s = blockIdx.z ? s1 : s0;
    short* d = blockIdx.z ? d1 : d0;
    const int idx = blockIdx.x * BDIM + threadIdx.x;
    if (idx >= 4 * 32 * H * W) return;
    const int c = idx & 31;
    int t = idx >> 5;
    const int x = t % W; t /= W;
    const int y = t % H;
    const int b = t / H;
    d[idx] = (short)f2bf(s[(((size_t)b * 32 + c) * H + y) * W + x]);
}

// Bilinear 2x upsample, NHWC bf16, half-pixel centers, edge clamp.
__global__ __launch_bounds__(BDIM)
void up2b_k(const short* __restrict__ in, short* __restrict__ out,
            int Hin, int Win)
{
    const int Hout = 2 * Hin, Wout = 2 * Win;
    const int idx = blockIdx.x * BDIM + threadIdx.x;
    if (idx >= 4 * Hout * Wout * 4) return;
    const int cg = idx & 3;
    int t = idx >> 2;
    const int x = t % Wout; t /= Wout;
    const int y = t % Hout;
    const int b = t / Hout;

    const float sy = (y + 0.5f) * 0.5f - 0.5f;
    const float sx = (x + 0.5f) * 0.5f - 0.5f;
    const float y0f = floorf(sy), x0f = floorf(sx);
    const float wy = sy - y0f, wx = sx - x0f;
    const int y0 = (int)y0f, x0 = (int)x0f;
    const int y0c = min(max(y0, 0), Hin - 1);
    const int y1c = min(max(y0 + 1, 0), Hin - 1);
    const int x0c = min(max(x0, 0), Win - 1);
    const int x1c = min(max(x0 + 1, 0), Win - 1);

    const short* base = in + (size_t)b * Hin * Win * 32 + cg * 8;
    short8v v00 = *(const short8v*)(base + ((size_t)y0c * Win + x0c) * 32);
    short8v v01 = *(const short8v*)(base + ((size_t)y0c * Win + x1c) * 32);
    short8v v10 = *(const short8v*)(base + ((size_t)y1c * Win + x0c) * 32);
    short8v v11 = *(const short8v*)(base + ((size_t)y1c * Win + x1c) * 32);

    short8v o;
#pragma unroll
    for (int j = 0; j < 8; ++j) {
        float f = (1.f - wy) * ((1.f - wx) * bf2f((unsigned short)v00[j]) +
                                wx * bf2f((unsigned short)v01[j]))
                + wy * ((1.f - wx) * bf2f((unsigned short)v10[j]) +
                        wx * bf2f((unsigned short)v11[j]));
        o[j] = (short)f2bf(f);
    }
    short* op = out + (size_t)b * Hout * Wout * 32 + ((size_t)y * Wout + x) * 32 + cg * 8;
    *(short8v*)op = o;
}

// ---------------------------------------------------------------------------
// Modulated deformable conv (DCNv2) on MFMA. Wave = 16 consecutive x-pixels;
// lane l: pixel (l&15), deformable group (l>>4) -> B-frag k-slot (l>>4)*8+j.
// 2 MFMAs per tap (32 couts, K=32 = all input channels). fp32 planar out.
__global__ __launch_bounds__(BDIM, 4)
void dcnm_k(const short* __restrict__ xb,   // NHWC bf16 [B][H][W][32]
            const short* __restrict__ om,   // NHWC bf16 [B][H][W][112]
            const short* __restrict__ wf,   // [9][2][64][8] bf16 frags
            const float* __restrict__ bias,
            float* __restrict__ out, int H, int W)
{
    const int lane = threadIdx.x & 63;
    const int wid  = blockIdx.x * 4 + (threadIdx.x >> 6);
    const int segs = W / 16;
    const int b = wid / (H * segs);
    int r = wid - b * (H * segs);
    const int y = r / segs;
    const int x = (r - y * segs) * 16 + (lane & 15);
    const int g = lane >> 4;
    const size_t plane = (size_t)H * W;

    f32x4 acc0 = (f32x4){0.f, 0.f, 0.f, 0.f};
    f32x4 acc1 = (f32x4){0.f, 0.f, 0.f, 0.f};

    const short* omb = om + ((size_t)b * plane + (size_t)y * W + x) * 112;
    const short* xbb = xb + (size_t)b * plane * 32 + g * 8;

#pragma unroll
    for (int k = 0; k < 9; ++k) {
        const float offy = bf2f((unsigned short)omb[g * 9 + k]);
        const float offx = bf2f((unsigned short)omb[36 + g * 9 + k]);
        const float ml   = bf2f((unsigned short)omb[72 + g * 9 + k]);
        const float m = 1.f / (1.f + __expf(-ml));

        const float py = offy + (float)y + (float)(k / 3 - 1);
        const float px = offx + (float)x + (float)(k % 3 - 1);
        const float y0f = floorf(py), x0f = floorf(px);
        const int y0 = (int)y0f, x0 = (int)x0f;
        const float wy1 = py - y0f, wx1 = px - x0f;
        const float wy0 = 1.f - wy1, wx0 = 1.f - wx1;

        const bool y0ok = (unsigned)y0 < (unsigned)H;
        const bool y1ok = (unsigned)(y0 + 1) < (unsigned)H;
        const bool x0ok = (unsigned)x0 < (unsigned)W;
        const bool x1ok = (unsigned)(x0 + 1) < (unsigned)W;
        const int y0c = min(max(y0, 0), H - 1);
        const int y1c = min(max(y0 + 1, 0), H - 1);
        const int x0c = min(max(x0, 0), W - 1);
        const int x1c = min(max(x0 + 1, 0), W - 1);

        const float w00 = wy0 * wx0 * ((y0ok && x0ok) ? 1.f : 0.f) * m;
        const float w01 = wy0 * wx1 * ((y0ok && x1ok) ? 1.f : 0.f) * m;
        const float w10 = wy1 * wx0 * ((y1ok && x0ok) ? 1.f : 0.f) * m;
        const float w11 = wy1 * wx1 * ((y1ok && x1ok) ? 1.f : 0.f) * m;

        short8v v00 = *(const short8v*)(xbb + ((size_t)y0c * W + x0c) * 32);
        short8v v01 = *(const short8v*)(xbb + ((size_t)y0c * W + x1c) * 32);
        short8v v10 = *(const short8v*)(xbb + ((size_t)y1c * W + x0c) * 32);
        short8v v11 = *(const short8v*)(xbb + ((size_t)y1c * W + x1c) * 32);

        short8v bv;
#pragma unroll
        for (int j = 0; j < 8; ++j) {
            float s = w00 * bf2f((unsigned short)v00[j])
                    + w01 * bf2f((unsigned short)v01[j])
                    + w10 * bf2f((unsigned short)v10[j])
                    + w11 * bf2f((unsigned short)v11[j]);
            bv[j] = (short)f2bf(s);
        }

        short8v a0 = *(const short8v*)(wf + (((size_t)k * 2 + 0) * 64 + lane) * 8);
        short8v a1 = *(const short8v*)(wf + (((size_t)k * 2 + 1) * 64 + lane) * 8);
        acc0 = __builtin_amdgcn_mfma_f32_16x16x32_bf16(a0, bv, acc0, 0, 0, 0);
        acc1 = __builtin_amdgcn_mfma_f32_16x16x32_bf16(a1, bv, acc1, 0, 0, 0);
    }

    float* op = out + (size_t)b * 32 * plane + (size_t)y * W + x;
#pragma unroll
    for (int j = 0; j < 4; ++j) {
        const int co0 = g * 4 + j;
        const int co1 = 16 + g * 4 + j;
        op[(size_t)co0 * plane] = acc0[j] + bias[co0];
        op[(size_t)co1 * plane] = acc1[j] + bias[co1];
    }
}

// ---------------------------------------------------------------------------

extern "C" void kernel_launch(void* const* d_in, const int* in_sizes, int n_in,
                              void* d_out, int out_size, void* d_ws, size_t ws_size,
                              hipStream_t stream)
{
    const float* fea1  = (const float*)d_in[0];
    const float* fea2  = (const float*)d_in[1];
    const float* w1_1  = (const float*)d_in[2];  const float* b1_1 = (const float*)d_in[3];
    const float* w2_1  = (const float*)d_in[4];  const float* b2_1 = (const float*)d_in[5];
    const float* w3_1  = (const float*)d_in[6];  const float* b3_1 = (const float*)d_in[7];
    const float* w4_1  = (const float*)d_in[8];  const float* b4_1 = (const float*)d_in[9];
    const float* w6_1  = (const float*)d_in[10]; const float* b6_1 = (const float*)d_in[11];
    const float* w7_1  = (const float*)d_in[12]; const float* b7_1 = (const float*)d_in[13];
    const float* w1_2  = (const float*)d_in[14]; const float* b1_2 = (const float*)d_in[15];
    const float* w2_2  = (const float*)d_in[16]; const float* b2_2 = (const float*)d_in[17];
    const float* w3_2  = (const float*)d_in[18]; const float* b3_2 = (const float*)d_in[19];
    const float* w4_2  = (const float*)d_in[20]; const float* b4_2 = (const float*)d_in[21];
    const float* w_om  = (const float*)d_in[22]; const float* b_om = (const float*)d_in[23];
    const float* w_dcn = (const float*)d_in[24]; const float* b_dcn= (const float*)d_in[25];

    const int H = 192, W = 192;
    char* ws = (char*)d_ws;

    // byte offsets; fea2b stays live to the end (dcnm samples it)
    short* fea1b = (short*)(ws + 0);          // bf16 NHWC 192  (9.44 MB)
    short* fea2b = (short*)(ws + 9437184);    // LIVE TO END
    short* bufA  = (short*)(ws + 18874368);   // off      192
    short* bufB  = (short*)(ws + 28311552);   // off1     192 (lives to conv3_2)
    short* bufC  = (short*)(ws + 0);          // off2a    96  (fea1b dead)
    short* bufD  = (short*)(ws + 2359296);    // off2     96
    short* bufE  = (short*)(ws + 4718592);    // off3a    48
    short* bufF  = (short*)(ws + 5308416);    // off3     48
    short* bufG  = (short*)(ws + 5898240);    // up96     96
    short* bufH  = (short*)(ws + 0);          // conv1_2 out 96 (bufC dead)
    short* bufI  = (short*)(ws + 4718592);    // conv2_2 out 96 (E/F dead)
    short* bufJ  = (short*)(ws + 37748736);   // up192 (om slot, written later)
    short* bufK  = (short*)(ws + 18874368);   // conv3_2 out (bufA dead)
    short* bufL  = (short*)(ws + 0);          // base_offset 192 (H/D/I dead)
    short* om    = (short*)(ws + 37748736);   // NHWC bf16 stride 112 (33.0 MB)
    short* wfrag = (short*)(ws + 70778880);   // conv weight frags (313344 B)
    short* wfdcn = (short*)(ws + 71092224);   // dcn weight frags (18.4 KB)

    // fragment offsets in shorts per conv (om has nh=8 -> 36864 shorts)
    const int WOFF[11] = {0, 18432, 27648, 36864, 46080, 55296,
                          64512, 82944, 92160, 110592, 119808};

    dim3 blk(BDIM, 1, 1);

    // 0. weight prep + input conversions
    {
        WPArgs a;
        const float* srcs[11] = {w1_1, w2_1, w3_1, w4_1, w6_1, w7_1,
                                 w1_2, w2_2, w3_2, w4_2, w_om};
        const int NP[11] = {2,1,1,1,1,1,2,1,2,1,1};
        const int NH[11] = {2,2,2,2,2,2,2,2,2,2,8};
        const int Os[11] = {32,32,32,32,32,32,32,32,32,32,108};
        for (int i = 0; i < 11; ++i) {
            a.src[i] = srcs[i]; a.off[i] = WOFF[i];
            a.npass[i] = NP[i]; a.nhalf[i] = NH[i]; a.O[i] = Os[i];
        }
        wprep_k<<<dim3(144, 1, 11), blk, 0, stream>>>(a, wfrag);
        cvtnhwc_k<<<dim3(18432, 1, 2), blk, 0, stream>>>(fea1, fea2, fea1b, fea2b, H, W);
        wdp_k<<<dim3(36), blk, 0, stream>>>(w_dcn, wfdcn);
    }

    // 1. off = lrelu(conv1_1(cat(fea1, fea2)))           192
    convm_k<2,2,2,1,true><<<dim3(1152), blk, 0, stream>>>(
        fea1b, fea2b, wfrag + WOFF[0], b1_1, bufA, 192,192,192,192, 32, 32, 2);
    // 2. off1 = lrelu(conv2_1(off))                      192
    convm_k<1,2,2,1,true><<<dim3(1152), blk, 0, stream>>>(
        bufA, nullptr, wfrag + WOFF[1], b2_1, bufB, 192,192,192,192, 32, 32, 2);
    // 3. off2a = lrelu(conv3_1(off1, s2))                96
    convm_k<1,2,1,2,true><<<dim3(576), blk, 0, stream>>>(
        bufB, nullptr, wfrag + WOFF[2], b3_1, bufC, 192,192,96,96, 32, 32, 2);
    // 4. off2 = lrelu(conv4_1(off2a))                    96
    convm_k<1,2,1,1,true><<<dim3(576), blk, 0, stream>>>(
        bufC, nullptr, wfrag + WOFF[3], b4_1, bufD, 96,96,96,96, 32, 32, 2);
    // 5. off3a = lrelu(conv6_1(off2, s2))                48
    convm_k<1,2,1,2,true><<<dim3(144), blk, 0, stream>>>(
        bufD, nullptr, wfrag + WOFF[4], b6_1, bufE, 96,96,48,48, 32, 32, 2);
    // 6. off3 = lrelu(conv7_1(off3a))                    48
    convm_k<1,2,1,1,true><<<dim3(144), blk, 0, stream>>>(
        bufE, nullptr, wfrag + WOFF[5], b7_1, bufF, 48,48,48,48, 32, 32, 2);
    // 7. up96 = up2(off3)
    up2b_k<<<dim3(576), blk, 0, stream>>>(bufF, bufG, 48, 48);
    // 8. t = lrelu(conv1_2(cat(up96, off2)))             96
    convm_k<2,2,1,1,true><<<dim3(576), blk, 0, stream>>>(
        bufG, bufD, wfrag + WOFF[6], b1_2, bufH, 96,96,96,96, 32, 32, 2);
    // 9. t2 = lrelu(conv2_2(t))                          96
    convm_k<1,2,1,1,true><<<dim3(576), blk, 0, stream>>>(
        bufH, nullptr, wfrag + WOFF[7], b2_2, bufI, 96,96,96,96, 32, 32, 2);
    // 10. up192 = up2(t2)
    up2b_k<<<dim3(2304), blk, 0, stream>>>(bufI, bufJ, 96, 96);
    // 11. off = lrelu(conv3_2(cat(up192, off1)))         192
    convm_k<2,2,2,1,true><<<dim3(1152), blk, 0, stream>>>(
        bufJ, bufB, wfrag + WOFF[8], b3_2, bufK, 192,192,192,192, 32, 32, 2);
    // 12. base_offset = conv4_2(off)    (no lrelu)       192
    convm_k<1,2,2,1,false><<<dim3(1152), blk, 0, stream>>>(
        bufK, nullptr, wfrag + WOFF[9], b4_2, bufL, 192,192,192,192, 32, 32, 2);
    // 13. om = conv_om(base_offset)  32 -> 108 (pad 112), 4 cout-chunks via z
    convm_k<1,2,2,1,false><<<dim3(1152, 1, 4), blk, 0, stream>>>(
        bufL, nullptr, wfrag + WOFF[10], b_om, om, 192,192,192,192, 112, 108, 8);
    // 14. out = deform_conv(fea2, om)
    dcnm_k<<<dim3(2304), blk, 0, stream>>>(
        fea2b, om, wfdcn, b_dcn, (float*)d_out, H, W);
}

// Round 7
// 325.145 us; speedup vs baseline: 1.0389x; 1.0389x over previous
//
#include <hip/hip_runtime.h>
#include <math.h>

// ---------------------------------------------------------------------------
// DCN_Align on MI355X. Convs AND deformable conv on MFMA bf16 (16x16x32).
// Conv: all 9 B-taps loaded upfront (single latency exposure), NT=1, NHWC.
// DCN: conv_om FUSED into dcnm -- phase 1 computes the 108 offset/mask
// channels for the wave's 16 pixels on MFMA into LDS; phase 2 samples and
// does PV on MFMA. The 33 MB om tensor never exists.
// ---------------------------------------------------------------------------

#define BDIM 256

typedef __attribute__((ext_vector_type(8))) short short8v;
typedef __attribute__((ext_vector_type(4))) float f32x4;

__device__ __forceinline__ unsigned short f2bf(float f) {
    unsigned u = __builtin_bit_cast(unsigned, f);
    u = (u + 0x7FFF + ((u >> 16) & 1)) >> 16;   // round-to-nearest-even
    return (unsigned short)u;
}
__device__ __forceinline__ float bf2f(unsigned short h) {
    unsigned u = ((unsigned)h) << 16;
    return __builtin_bit_cast(float, u);
}

// ---------------------------------------------------------------------------
// MFMA conv: wave = 16 consecutive x-pixels in one output row.
// B-frag: lane l -> pixel (l&15), channels (l>>4)*8+j (16B NHWC load).
// A-frag: lane l -> cout h*16+(l&15), channels (l>>4)*8+j (pre-packed).
// C/D: col(pixel)=lane&15, row(cout)=(lane>>4)*4+reg  [verified in-round].
template<int NPASS, int NHALF, int STRIDE, bool LRELU>
__global__ __launch_bounds__(BDIM, 4)
void convm_k(const short* __restrict__ in0, const short* __restrict__ in1,
             const short* __restrict__ wf,   // [pass][tap][NHALF][lane][8] bf16
             const float* __restrict__ bias,
             short* __restrict__ out,        // NHWC bf16, channel stride OCS
             int Hin, int Win, int Hout, int Wout, int OCS)
{
    const int lane = threadIdx.x & 63;
    const int wid  = blockIdx.x * 4 + (threadIdx.x >> 6);
    const int segs = Wout >> 4;
    const int b  = wid / (Hout * segs);
    int r = wid - b * (Hout * segs);
    const int oy = r / segs;
    const int x0 = (r - oy * segs) * 16;
    const int lp = lane & 15;
    const int g  = lane >> 4;

    int rowOff[3]; bool rowOk[3];
#pragma unroll
    for (int ty = 0; ty < 3; ++ty) {
        const int iy = oy * STRIDE + ty - 1;
        rowOk[ty] = (unsigned)iy < (unsigned)Hin;
        rowOff[ty] = min(max(iy, 0), Hin - 1) * Win;
    }
    int colOff[3]; bool colOk[3];
#pragma unroll
    for (int tx = 0; tx < 3; ++tx) {
        const int ix = (x0 + lp) * STRIDE + tx - 1;
        colOk[tx] = (unsigned)ix < (unsigned)Win;
        colOff[tx] = min(max(ix, 0), Win - 1) * 32 + g * 8;
    }

    f32x4 acc[NHALF];
#pragma unroll
    for (int h = 0; h < NHALF; ++h) acc[h] = (f32x4){0.f, 0.f, 0.f, 0.f};

    const size_t inPlane = (size_t)Hin * Win * 32;
    const short8v zero = {};

#pragma unroll
    for (int pass = 0; pass < NPASS; ++pass) {
        const short* inp = (pass == 0 ? in0 : in1) + (size_t)b * inPlane;

        short8v bv[9];
#pragma unroll
        for (int t = 0; t < 9; ++t) {
            const int ty = t / 3, tx = t % 3;
            short8v v = *(const short8v*)(inp + (size_t)rowOff[ty] * 32 + colOff[tx]);
            bv[t] = (rowOk[ty] & colOk[tx]) ? v : zero;
        }
#pragma unroll
        for (int t = 0; t < 9; ++t) {
#pragma unroll
            for (int h = 0; h < NHALF; ++h) {
                short8v av = *(const short8v*)(
                    wf + ((((size_t)pass * 9 + t) * NHALF + h) * 64 + lane) * 8);
                acc[h] = __builtin_amdgcn_mfma_f32_16x16x32_bf16(av, bv[t], acc[h], 0, 0, 0);
            }
        }
    }

    short* op = out + (((size_t)b * Hout + oy) * Wout + x0 + lp) * OCS;
#pragma unroll
    for (int h = 0; h < NHALF; ++h) {
        const int co0 = h * 16 + g * 4;
        ushort4 st;
#pragma unroll
        for (int j = 0; j < 4; ++j) {
            float v = acc[h][j] + bias[co0 + j];
            if (LRELU) v = (v >= 0.f) ? v : 0.1f * v;
            ((unsigned short*)&st)[j] = f2bf(v);
        }
        *(ushort4*)(op + co0) = st;
    }
}

// ---------------------------------------------------------------------------
// Weight prep: [O][I][3][3] fp32 -> fragment layout bf16 [pass][t][h][lane][8].
struct WPArgs {
    const float* src[11];
    int off[11];      // dst offset in shorts
    int npass[11], nhalf[11], O[11];
};

__global__ __launch_bounds__(BDIM)
void wprep_k(WPArgs a, short* __restrict__ wbase)
{
    const int z = blockIdx.z;
    const int n = a.npass[z] * 9 * a.nhalf[z] * 512;
    const int idx = blockIdx.x * BDIM + threadIdx.x;
    if (idx >= n) return;
    const int j = idx & 7;
    const int l = (idx >> 3) & 63;
    int r = idx >> 9;
    const int h = r % a.nhalf[z]; r /= a.nhalf[z];
    const int t = r % 9;
    const int pass = r / 9;
    const int I = a.npass[z] * 32;
    const int cout = h * 16 + (l & 15);
    const int cin  = pass * 32 + (l >> 4) * 8 + j;
    float v = (cout < a.O[z]) ? a.src[z][((size_t)cout * I + cin) * 9 + t] : 0.f;
    wbase[a.off[z] + idx] = (short)f2bf(v);
}

// dcn weights [32o][32i][3][3] -> [tap][half][lane][8] bf16 frags
__global__ __launch_bounds__(BDIM)
void wdp_k(const float* __restrict__ w, short* __restrict__ dst)
{
    const int idx = blockIdx.x * BDIM + threadIdx.x;
    if (idx >= 9 * 2 * 64 * 8) return;
    const int j = idx & 7;
    const int l = (idx >> 3) & 63;
    const int h = (idx >> 9) & 1;
    const int k = idx >> 10;
    const int cout = h * 16 + (l & 15);
    const int cin  = (l >> 4) * 8 + j;
    dst[idx] = (short)f2bf(w[((size_t)cout * 32 + cin) * 9 + k]);
}

// fea NCHW fp32 -> NHWC bf16 (two tensors in one launch via z)
__global__ __launch_bounds__(BDIM)
void cvtnhwc_k(const float* __restrict__ s0, const float* __restrict__ s1,
               short* __restrict__ d0, short* __restrict__ d1, int H, int W)
{
    const float* s = blockIdx.z ? s1 : s0;
    short* d = blockIdx.z ? d1 : d0;
    const int idx = blockIdx.x * BDIM + threadIdx.x;
    if (idx >= 4 * 32 * H * W) return;
    const int c = idx & 31;
    int t = idx >> 5;
    const int x = t % W; t /= W;
    const int y = t % H;
    const int b = t / H;
    d[idx] = (short)f2bf(s[(((size_t)b * 32 + c) * H + y) * W + x]);
}

// Bilinear 2x upsample, NHWC bf16, half-pixel centers, edge clamp.
__global__ __launch_bounds__(BDIM)
void up2b_k(const short* __restrict__ in, short* __restrict__ out,
            int Hin, int Win)
{
    const int Hout = 2 * Hin, Wout = 2 * Win;
    const int idx = blockIdx.x * BDIM + threadIdx.x;
    if (idx >= 4 * Hout * Wout * 4) return;
    const int cg = idx & 3;
    int t = idx >> 2;
    const int x = t % Wout; t /= Wout;
    const int y = t % Hout;
    const int b = t / Hout;

    const float sy = (y + 0.5f) * 0.5f - 0.5f;
    const float sx = (x + 0.5f) * 0.5f - 0.5f;
    const float y0f = floorf(sy), x0f = floorf(sx);
    const float wy = sy - y0f, wx = sx - x0f;
    const int y0 = (int)y0f, x0 = (int)x0f;
    const int y0c = min(max(y0, 0), Hin - 1);
    const int y1c = min(max(y0 + 1, 0), Hin - 1);
    const int x0c = min(max(x0, 0), Win - 1);
    const int x1c = min(max(x0 + 1, 0), Win - 1);

    const short* base = in + (size_t)b * Hin * Win * 32 + cg * 8;
    short8v v00 = *(const short8v*)(base + ((size_t)y0c * Win + x0c) * 32);
    short8v v01 = *(const short8v*)(base + ((size_t)y0c * Win + x1c) * 32);
    short8v v10 = *(const short8v*)(base + ((size_t)y1c * Win + x0c) * 32);
    short8v v11 = *(const short8v*)(base + ((size_t)y1c * Win + x1c) * 32);

    short8v o;
#pragma unroll
    for (int j = 0; j < 8; ++j) {
        float f = (1.f - wy) * ((1.f - wx) * bf2f((unsigned short)v00[j]) +
                                wx * bf2f((unsigned short)v01[j]))
                + wy * ((1.f - wx) * bf2f((unsigned short)v10[j]) +
                        wx * bf2f((unsigned short)v11[j]));
        o[j] = (short)f2bf(f);
    }
    short* op = out + (size_t)b * Hout * Wout * 32 + ((size_t)y * Wout + x) * 32 + cg * 8;
    *(short8v*)op = o;
}

// ---------------------------------------------------------------------------
// Fused conv_om + modulated deformable conv (DCNv2) on MFMA.
// Wave = 16 consecutive x-pixels. Phase 1: om = conv3x3(base_offset) for
// these pixels (9 upfront B-loads, 63 MFMAs) -> bias -> bf16 -> LDS
// [wave][pixel][112]. Phase 2: lane l = pixel (l&15), group (l>>4);
// bilinear-sample fea2 with LDS offsets/masks, 2 MFMAs per tap.
__global__ __launch_bounds__(BDIM, 4)
void dcnm_k(const short* __restrict__ xb,    // fea2 NHWC bf16 [B][H][W][32]
            const short* __restrict__ bo,    // base_offset NHWC bf16 [B][H][W][32]
            const short* __restrict__ wfo,   // om A-frags [9][7][64][8]
            const float* __restrict__ obias, // om bias (108)
            const short* __restrict__ wfd,   // dcn A-frags [9][2][64][8]
            const float* __restrict__ bias,  // dcn bias (32)
            float* __restrict__ out, int H, int W)
{
    __shared__ unsigned short omld[4][16][112];   // 14336 B

    const int lane = threadIdx.x & 63;
    const int wv   = threadIdx.x >> 6;
    const int wid  = blockIdx.x * 4 + wv;
    const int segs = W >> 4;
    const int b = wid / (H * segs);
    int r = wid - b * (H * segs);
    const int y = r / segs;
    const int x0 = (r - y * segs) * 16;
    const int lp = lane & 15;
    const int g  = lane >> 4;
    const int x  = x0 + lp;
    const size_t plane = (size_t)H * W;
    const short8v zero = {};

    // ---------------- phase 1: om = conv_om(base_offset) ----------------
    {
        int rowOff[3]; bool rowOk[3];
#pragma unroll
        for (int ty = 0; ty < 3; ++ty) {
            const int iy = y + ty - 1;
            rowOk[ty] = (unsigned)iy < (unsigned)H;
            rowOff[ty] = min(max(iy, 0), H - 1) * W;
        }
        int colOff[3]; bool colOk[3];
#pragma unroll
        for (int tx = 0; tx < 3; ++tx) {
            const int ix = x + tx - 1;
            colOk[tx] = (unsigned)ix < (unsigned)W;
            colOff[tx] = min(max(ix, 0), W - 1) * 32 + g * 8;
        }
        const short* inp = bo + (size_t)b * plane * 32;
        short8v bv[9];
#pragma unroll
        for (int t = 0; t < 9; ++t) {
            const int ty = t / 3, tx = t % 3;
            short8v v = *(const short8v*)(inp + (size_t)rowOff[ty] * 32 + colOff[tx]);
            bv[t] = (rowOk[ty] & colOk[tx]) ? v : zero;
        }
        f32x4 acc[7];
#pragma unroll
        for (int h = 0; h < 7; ++h) acc[h] = (f32x4){0.f, 0.f, 0.f, 0.f};
#pragma unroll
        for (int t = 0; t < 9; ++t) {
#pragma unroll
            for (int h = 0; h < 7; ++h) {
                short8v av = *(const short8v*)(wfo + (((size_t)t * 7 + h) * 64 + lane) * 8);
                acc[h] = __builtin_amdgcn_mfma_f32_16x16x32_bf16(av, bv[t], acc[h], 0, 0, 0);
            }
        }
#pragma unroll
        for (int h = 0; h < 7; ++h) {
            const int co0 = h * 16 + g * 4;
            ushort4 st;
#pragma unroll
            for (int j = 0; j < 4; ++j)
                ((unsigned short*)&st)[j] = f2bf(acc[h][j] + obias[min(co0 + j, 107)]);
            *(ushort4*)&omld[wv][lp][co0] = st;
        }
    }
    __syncthreads();

    // ---------------- phase 2: deformable sampling + PV ----------------
    f32x4 p0 = (f32x4){0.f, 0.f, 0.f, 0.f};
    f32x4 p1 = (f32x4){0.f, 0.f, 0.f, 0.f};
    const short* xbb = xb + (size_t)b * plane * 32 + g * 8;

#pragma unroll
    for (int k = 0; k < 9; ++k) {
        const float offy = bf2f(omld[wv][lp][g * 9 + k]);
        const float offx = bf2f(omld[wv][lp][36 + g * 9 + k]);
        const float ml   = bf2f(omld[wv][lp][72 + g * 9 + k]);
        const float m = 1.f / (1.f + __expf(-ml));

        const float py = offy + (float)y + (float)(k / 3 - 1);
        const float px = offx + (float)x + (float)(k % 3 - 1);
        const float y0f = floorf(py), x0f = floorf(px);
        const int y0 = (int)y0f, x0i = (int)x0f;
        const float wy1 = py - y0f, wx1 = px - x0f;
        const float wy0 = 1.f - wy1, wx0 = 1.f - wx1;

        const bool y0ok = (unsigned)y0 < (unsigned)H;
        const bool y1ok = (unsigned)(y0 + 1) < (unsigned)H;
        const bool x0ok = (unsigned)x0i < (unsigned)W;
        const bool x1ok = (unsigned)(x0i + 1) < (unsigned)W;
        const int y0c = min(max(y0, 0), H - 1);
        const int y1c = min(max(y0 + 1, 0), H - 1);
        const int x0c = min(max(x0i, 0), W - 1);
        const int x1c = min(max(x0i + 1, 0), W - 1);

        const float w00 = wy0 * wx0 * ((y0ok && x0ok) ? 1.f : 0.f) * m;
        const float w01 = wy0 * wx1 * ((y0ok && x1ok) ? 1.f : 0.f) * m;
        const float w10 = wy1 * wx0 * ((y1ok && x0ok) ? 1.f : 0.f) * m;
        const float w11 = wy1 * wx1 * ((y1ok && x1ok) ? 1.f : 0.f) * m;

        short8v v00 = *(const short8v*)(xbb + ((size_t)y0c * W + x0c) * 32);
        short8v v01 = *(const short8v*)(xbb + ((size_t)y0c * W + x1c) * 32);
        short8v v10 = *(const short8v*)(xbb + ((size_t)y1c * W + x0c) * 32);
        short8v v11 = *(const short8v*)(xbb + ((size_t)y1c * W + x1c) * 32);

        short8v bv;
#pragma unroll
        for (int j = 0; j < 8; ++j) {
            float s = w00 * bf2f((unsigned short)v00[j])
                    + w01 * bf2f((unsigned short)v01[j])
                    + w10 * bf2f((unsigned short)v10[j])
                    + w11 * bf2f((unsigned short)v11[j]);
            bv[j] = (short)f2bf(s);
        }

        short8v a0 = *(const short8v*)(wfd + (((size_t)k * 2 + 0) * 64 + lane) * 8);
        short8v a1 = *(const short8v*)(wfd + (((size_t)k * 2 + 1) * 64 + lane) * 8);
        p0 = __builtin_amdgcn_mfma_f32_16x16x32_bf16(a0, bv, p0, 0, 0, 0);
        p1 = __builtin_amdgcn_mfma_f32_16x16x32_bf16(a1, bv, p1, 0, 0, 0);
    }

    float* op = out + (size_t)b * 32 * plane + (size_t)y * W + x;
#pragma unroll
    for (int j = 0; j < 4; ++j) {
        const int co0 = g * 4 + j;
        const int co1 = 16 + g * 4 + j;
        op[(size_t)co0 * plane] = p0[j] + bias[co0];
        op[(size_t)co1 * plane] = p1[j] + bias[co1];
    }
}

// ---------------------------------------------------------------------------

extern "C" void kernel_launch(void* const* d_in, const int* in_sizes, int n_in,
                              void* d_out, int out_size, void* d_ws, size_t ws_size,
                              hipStream_t stream)
{
    const float* fea1  = (const float*)d_in[0];
    const float* fea2  = (const float*)d_in[1];
    const float* w1_1  = (const float*)d_in[2];  const float* b1_1 = (const float*)d_in[3];
    const float* w2_1  = (const float*)d_in[4];  const float* b2_1 = (const float*)d_in[5];
    const float* w3_1  = (const float*)d_in[6];  const float* b3_1 = (const float*)d_in[7];
    const float* w4_1  = (const float*)d_in[8];  const float* b4_1 = (const float*)d_in[9];
    const float* w6_1  = (const float*)d_in[10]; const float* b6_1 = (const float*)d_in[11];
    const float* w7_1  = (const float*)d_in[12]; const float* b7_1 = (const float*)d_in[13];
    const float* w1_2  = (const float*)d_in[14]; const float* b1_2 = (const float*)d_in[15];
    const float* w2_2  = (const float*)d_in[16]; const float* b2_2 = (const float*)d_in[17];
    const float* w3_2  = (const float*)d_in[18]; const float* b3_2 = (const float*)d_in[19];
    const float* w4_2  = (const float*)d_in[20]; const float* b4_2 = (const float*)d_in[21];
    const float* w_om  = (const float*)d_in[22]; const float* b_om = (const float*)d_in[23];
    const float* w_dcn = (const float*)d_in[24]; const float* b_dcn= (const float*)d_in[25];

    const int H = 192, W = 192;
    char* ws = (char*)d_ws;

    // byte offsets; fea2b stays live to the end (dcnm samples it)
    short* fea1b = (short*)(ws + 0);          // bf16 NHWC 192  (9.44 MB)
    short* fea2b = (short*)(ws + 9437184);    // LIVE TO END
    short* bufA  = (short*)(ws + 18874368);   // off      192
    short* bufB  = (short*)(ws + 28311552);   // off1     192 (lives to conv3_2)
    short* bufC  = (short*)(ws + 0);          // off2a    96  (fea1b dead)
    short* bufD  = (short*)(ws + 2359296);    // off2     96
    short* bufE  = (short*)(ws + 4718592);    // off3a    48
    short* bufF  = (short*)(ws + 5308416);    // off3     48
    short* bufG  = (short*)(ws + 5898240);    // up96     96
    short* bufH  = (short*)(ws + 0);          // conv1_2 out 96 (bufC dead)
    short* bufI  = (short*)(ws + 4718592);    // conv2_2 out 96 (E/F dead)
    short* bufJ  = (short*)(ws + 37748736);   // up192
    short* bufK  = (short*)(ws + 18874368);   // conv3_2 out (bufA dead)
    short* bufL  = (short*)(ws + 0);          // base_offset 192 (H/D/I dead)
    short* wfrag = (short*)(ws + 70778880);   // conv weight frags (304128 B)
    short* wfdcn = (short*)(ws + 71083008);   // dcn weight frags (18432 B)

    // fragment offsets in shorts per conv (om entry has nh=7 -> 32256 shorts)
    const int WOFF[11] = {0, 18432, 27648, 36864, 46080, 55296,
                          64512, 82944, 92160, 110592, 119808};

    dim3 blk(BDIM, 1, 1);

    // 0. weight prep + input conversions
    {
        WPArgs a;
        const float* srcs[11] = {w1_1, w2_1, w3_1, w4_1, w6_1, w7_1,
                                 w1_2, w2_2, w3_2, w4_2, w_om};
        const int NP[11] = {2,1,1,1,1,1,2,1,2,1,1};
        const int NH[11] = {2,2,2,2,2,2,2,2,2,2,7};
        const int Os[11] = {32,32,32,32,32,32,32,32,32,32,108};
        for (int i = 0; i < 11; ++i) {
            a.src[i] = srcs[i]; a.off[i] = WOFF[i];
            a.npass[i] = NP[i]; a.nhalf[i] = NH[i]; a.O[i] = Os[i];
        }
        wprep_k<<<dim3(126, 1, 11), blk, 0, stream>>>(a, wfrag);
        cvtnhwc_k<<<dim3(18432, 1, 2), blk, 0, stream>>>(fea1, fea2, fea1b, fea2b, H, W);
        wdp_k<<<dim3(36), blk, 0, stream>>>(w_dcn, wfdcn);
    }

    // 1. off = lrelu(conv1_1(cat(fea1, fea2)))           192
    convm_k<2,2,1,true><<<dim3(2304), blk, 0, stream>>>(
        fea1b, fea2b, wfrag + WOFF[0], b1_1, bufA, 192,192,192,192, 32);
    // 2. off1 = lrelu(conv2_1(off))                      192
    convm_k<1,2,1,true><<<dim3(2304), blk, 0, stream>>>(
        bufA, nullptr, wfrag + WOFF[1], b2_1, bufB, 192,192,192,192, 32);
    // 3. off2a = lrelu(conv3_1(off1, s2))                96
    convm_k<1,2,2,true><<<dim3(576), blk, 0, stream>>>(
        bufB, nullptr, wfrag + WOFF[2], b3_1, bufC, 192,192,96,96, 32);
    // 4. off2 = lrelu(conv4_1(off2a))                    96
    convm_k<1,2,1,true><<<dim3(576), blk, 0, stream>>>(
        bufC, nullptr, wfrag + WOFF[3], b4_1, bufD, 96,96,96,96, 32);
    // 5. off3a = lrelu(conv6_1(off2, s2))                48
    convm_k<1,2,2,true><<<dim3(144), blk, 0, stream>>>(
        bufD, nullptr, wfrag + WOFF[4], b6_1, bufE, 96,96,48,48, 32);
    // 6. off3 = lrelu(conv7_1(off3a))                    48
    convm_k<1,2,1,true><<<dim3(144), blk, 0, stream>>>(
        bufE, nullptr, wfrag + WOFF[5], b7_1, bufF, 48,48,48,48, 32);
    // 7. up96 = up2(off3)
    up2b_k<<<dim3(576), blk, 0, stream>>>(bufF, bufG, 48, 48);
    // 8. t = lrelu(conv1_2(cat(up96, off2)))             96
    convm_k<2,2,1,true><<<dim3(576), blk, 0, stream>>>(
        bufG, bufD, wfrag + WOFF[6], b1_2, bufH, 96,96,96,96, 32);
    // 9. t2 = lrelu(conv2_2(t))                          96
    convm_k<1,2,1,true><<<dim3(576), blk, 0, stream>>>(
        bufH, nullptr, wfrag + WOFF[7], b2_2, bufI, 96,96,96,96, 32);
    // 10. up192 = up2(t2)
    up2b_k<<<dim3(2304), blk, 0, stream>>>(bufI, bufJ, 96, 96);
    // 11. off = lrelu(conv3_2(cat(up192, off1)))         192
    convm_k<2,2,1,true><<<dim3(2304), blk, 0, stream>>>(
        bufJ, bufB, wfrag + WOFF[8], b3_2, bufK, 192,192,192,192, 32);
    // 12. base_offset = conv4_2(off)    (no lrelu)       192
    convm_k<1,2,1,false><<<dim3(2304), blk, 0, stream>>>(
        bufK, nullptr, wfrag + WOFF[9], b4_2, bufL, 192,192,192,192, 32);
    // 13. out = deform_conv(fea2, conv_om(base_offset))  [fused]
    dcnm_k<<<dim3(2304), blk, 0, stream>>>(
        fea2b, bufL, wfrag + WOFF[10], b_om, wfdcn, b_dcn, (float*)d_out, H, W);
}

// Round 8
// 313.306 us; speedup vs baseline: 1.0781x; 1.0378x over previous
//
#include <hip/hip_runtime.h>
#include <math.h>

// ---------------------------------------------------------------------------
// DCN_Align on MI355X. Convs AND deformable conv on MFMA bf16 (16x16x32).
// Big 192-res stride-1 convs: rolling-row sweep (wave = 16-px strip x YS
// rows; 3x3 B-window in registers, 3 new tap-loads per row, A in VGPR/L1).
// Small convs: upfront-9-tap convm. DCN: conv_om fused, wave-private LDS
// (no barrier).
// ---------------------------------------------------------------------------

#define BDIM 256

typedef __attribute__((ext_vector_type(8))) short short8v;
typedef __attribute__((ext_vector_type(4))) float f32x4;

__device__ __forceinline__ unsigned short f2bf(float f) {
    unsigned u = __builtin_bit_cast(unsigned, f);
    u = (u + 0x7FFF + ((u >> 16) & 1)) >> 16;   // round-to-nearest-even
    return (unsigned short)u;
}
__device__ __forceinline__ float bf2f(unsigned short h) {
    unsigned u = ((unsigned)h) << 16;
    return __builtin_bit_cast(float, u);
}

// ---------------------------------------------------------------------------
// Rolling-row MFMA conv, stride 1, Hin==Hout==H, 32 couts.
// Wave sweeps YS output rows of a 16-px column strip. B-window win[p][3][3]
// (slot = row % 3) rotates; per row only 3 new taps are loaded per pass.
// A: NPASS==1 -> cached in 18 VGPR-frags; NPASS==2 -> per-use global (L1).
template<int NPASS, bool LRELU, int YS>
__global__ __launch_bounds__(BDIM, 2)
void convr_k(const short* __restrict__ in0, const short* __restrict__ in1,
             const short* __restrict__ wf,   // [pass][tap][2][lane][8] bf16
             const float* __restrict__ bias,
             short* __restrict__ out, int H, int W)
{
    const int lane = threadIdx.x & 63;
    const int wid  = blockIdx.x * 4 + (threadIdx.x >> 6);
    const int segs = W >> 4;
    const int strips = (H / YS) * segs;
    const int b = wid / strips;
    int r = wid - b * strips;
    const int ys = r / segs;
    const int y0 = ys * YS;
    const int x0 = (r - ys * segs) * 16;
    const int lp = lane & 15;
    const int g  = lane >> 4;

    int colOff[3]; bool colOk[3];
#pragma unroll
    for (int tx = 0; tx < 3; ++tx) {
        const int ix = x0 + lp + tx - 1;
        colOk[tx] = (unsigned)ix < (unsigned)W;
        colOff[tx] = min(max(ix, 0), W - 1) * 32 + g * 8;
    }

    const size_t inPlane = (size_t)H * W * 32;
    const short8v zero = {};
    const short* inp0 = in0 + (size_t)b * inPlane;
    const short* inp1 = (NPASS > 1) ? in1 + (size_t)b * inPlane : nullptr;

    short8v awc[(NPASS == 1) ? 18 : 1];
    if constexpr (NPASS == 1) {
#pragma unroll
        for (int t = 0; t < 9; ++t)
#pragma unroll
            for (int h = 0; h < 2; ++h)
                awc[t * 2 + h] = *(const short8v*)(
                    wf + (((size_t)t * 2 + h) * 64 + lane) * 8);
    }

    short8v win[NPASS][3][3];

#define LOADROW(SLOT, IY) do {                                                \
        const int iy_ = (IY);                                                 \
        const bool rok_ = (unsigned)iy_ < (unsigned)H;                        \
        const int ro_ = min(max(iy_, 0), H - 1) * W;                          \
        _Pragma("unroll")                                                     \
        for (int tx = 0; tx < 3; ++tx) {                                      \
            short8v v_ = *(const short8v*)(inp0 + (size_t)ro_ * 32 + colOff[tx]); \
            win[0][SLOT][tx] = (rok_ & colOk[tx]) ? v_ : zero;                \
            if constexpr (NPASS > 1) {                                        \
                short8v w_ = *(const short8v*)(inp1 + (size_t)ro_ * 32 + colOff[tx]); \
                win[1][SLOT][tx] = (rok_ & colOk[tx]) ? w_ : zero;            \
            }                                                                 \
        }                                                                     \
    } while (0)

    LOADROW(0, y0 - 1);
    LOADROW(1, y0);

#pragma unroll
    for (int s = 0; s < YS; ++s) {
        LOADROW((s + 2) % 3, y0 + s + 1);

        f32x4 a0 = (f32x4){0.f, 0.f, 0.f, 0.f};
        f32x4 a1 = (f32x4){0.f, 0.f, 0.f, 0.f};
#pragma unroll
        for (int p = 0; p < NPASS; ++p) {
#pragma unroll
            for (int ty = 0; ty < 3; ++ty) {
#pragma unroll
                for (int tx = 0; tx < 3; ++tx) {
                    const int t = ty * 3 + tx;
                    const short8v bv = win[p][(s + ty) % 3][tx];
                    short8v av0, av1;
                    if constexpr (NPASS == 1) {
                        av0 = awc[t * 2 + 0];
                        av1 = awc[t * 2 + 1];
                    } else {
                        av0 = *(const short8v*)(
                            wf + ((((size_t)p * 9 + t) * 2 + 0) * 64 + lane) * 8);
                        av1 = *(const short8v*)(
                            wf + ((((size_t)p * 9 + t) * 2 + 1) * 64 + lane) * 8);
                    }
                    a0 = __builtin_amdgcn_mfma_f32_16x16x32_bf16(av0, bv, a0, 0, 0, 0);
                    a1 = __builtin_amdgcn_mfma_f32_16x16x32_bf16(av1, bv, a1, 0, 0, 0);
                }
            }
        }

        short* op = out + (((size_t)b * H + (y0 + s)) * W + x0 + lp) * 32;
        ushort4 st0, st1;
#pragma unroll
        for (int j = 0; j < 4; ++j) {
            float v0 = a0[j] + bias[g * 4 + j];
            float v1 = a1[j] + bias[16 + g * 4 + j];
            if (LRELU) {
                v0 = (v0 >= 0.f) ? v0 : 0.1f * v0;
                v1 = (v1 >= 0.f) ? v1 : 0.1f * v1;
            }
            ((unsigned short*)&st0)[j] = f2bf(v0);
            ((unsigned short*)&st1)[j] = f2bf(v1);
        }
        *(ushort4*)(op + g * 4) = st0;
        *(ushort4*)(op + 16 + g * 4) = st1;
    }
#undef LOADROW
}

// ---------------------------------------------------------------------------
// Upfront-9-tap MFMA conv (small resolutions / strided).
template<int NPASS, int NHALF, int STRIDE, bool LRELU>
__global__ __launch_bounds__(BDIM, 4)
void convm_k(const short* __restrict__ in0, const short* __restrict__ in1,
             const short* __restrict__ wf,
             const float* __restrict__ bias,
             short* __restrict__ out,
             int Hin, int Win, int Hout, int Wout, int OCS)
{
    const int lane = threadIdx.x & 63;
    const int wid  = blockIdx.x * 4 + (threadIdx.x >> 6);
    const int segs = Wout >> 4;
    const int b  = wid / (Hout * segs);
    int r = wid - b * (Hout * segs);
    const int oy = r / segs;
    const int x0 = (r - oy * segs) * 16;
    const int lp = lane & 15;
    const int g  = lane >> 4;

    int rowOff[3]; bool rowOk[3];
#pragma unroll
    for (int ty = 0; ty < 3; ++ty) {
        const int iy = oy * STRIDE + ty - 1;
        rowOk[ty] = (unsigned)iy < (unsigned)Hin;
        rowOff[ty] = min(max(iy, 0), Hin - 1) * Win;
    }
    int colOff[3]; bool colOk[3];
#pragma unroll
    for (int tx = 0; tx < 3; ++tx) {
        const int ix = (x0 + lp) * STRIDE + tx - 1;
        colOk[tx] = (unsigned)ix < (unsigned)Win;
        colOff[tx] = min(max(ix, 0), Win - 1) * 32 + g * 8;
    }

    f32x4 acc[NHALF];
#pragma unroll
    for (int h = 0; h < NHALF; ++h) acc[h] = (f32x4){0.f, 0.f, 0.f, 0.f};

    const size_t inPlane = (size_t)Hin * Win * 32;
    const short8v zero = {};

#pragma unroll
    for (int pass = 0; pass < NPASS; ++pass) {
        const short* inp = (pass == 0 ? in0 : in1) + (size_t)b * inPlane;

        short8v bv[9];
#pragma unroll
        for (int t = 0; t < 9; ++t) {
            const int ty = t / 3, tx = t % 3;
            short8v v = *(const short8v*)(inp + (size_t)rowOff[ty] * 32 + colOff[tx]);
            bv[t] = (rowOk[ty] & colOk[tx]) ? v : zero;
        }
#pragma unroll
        for (int t = 0; t < 9; ++t) {
#pragma unroll
            for (int h = 0; h < NHALF; ++h) {
                short8v av = *(const short8v*)(
                    wf + ((((size_t)pass * 9 + t) * NHALF + h) * 64 + lane) * 8);
                acc[h] = __builtin_amdgcn_mfma_f32_16x16x32_bf16(av, bv[t], acc[h], 0, 0, 0);
            }
        }
    }

    short* op = out + (((size_t)b * Hout + oy) * Wout + x0 + lp) * OCS;
#pragma unroll
    for (int h = 0; h < NHALF; ++h) {
        const int co0 = h * 16 + g * 4;
        ushort4 st;
#pragma unroll
        for (int j = 0; j < 4; ++j) {
            float v = acc[h][j] + bias[co0 + j];
            if (LRELU) v = (v >= 0.f) ? v : 0.1f * v;
            ((unsigned short*)&st)[j] = f2bf(v);
        }
        *(ushort4*)(op + co0) = st;
    }
}

// ---------------------------------------------------------------------------
// Weight prep: [O][I][3][3] fp32 -> fragment layout bf16 [pass][t][h][lane][8].
struct WPArgs {
    const float* src[11];
    int off[11];      // dst offset in shorts
    int npass[11], nhalf[11], O[11];
};

__global__ __launch_bounds__(BDIM)
void wprep_k(WPArgs a, short* __restrict__ wbase)
{
    const int z = blockIdx.z;
    const int n = a.npass[z] * 9 * a.nhalf[z] * 512;
    const int idx = blockIdx.x * BDIM + threadIdx.x;
    if (idx >= n) return;
    const int j = idx & 7;
    const int l = (idx >> 3) & 63;
    int r = idx >> 9;
    const int h = r % a.nhalf[z]; r /= a.nhalf[z];
    const int t = r % 9;
    const int pass = r / 9;
    const int I = a.npass[z] * 32;
    const int cout = h * 16 + (l & 15);
    const int cin  = pass * 32 + (l >> 4) * 8 + j;
    float v = (cout < a.O[z]) ? a.src[z][((size_t)cout * I + cin) * 9 + t] : 0.f;
    wbase[a.off[z] + idx] = (short)f2bf(v);
}

// dcn weights [32o][32i][3][3] -> [tap][half][lane][8] bf16 frags
__global__ __launch_bounds__(BDIM)
void wdp_k(const float* __restrict__ w, short* __restrict__ dst)
{
    const int idx = blockIdx.x * BDIM + threadIdx.x;
    if (idx >= 9 * 2 * 64 * 8) return;
    const int j = idx & 7;
    const int l = (idx >> 3) & 63;
    const int h = (idx >> 9) & 1;
    const int k = idx >> 10;
    const int cout = h * 16 + (l & 15);
    const int cin  = (l >> 4) * 8 + j;
    dst[idx] = (short)f2bf(w[((size_t)cout * 32 + cin) * 9 + k]);
}

// fea NCHW fp32 -> NHWC bf16 (two tensors in one launch via z)
__global__ __launch_bounds__(BDIM)
void cvtnhwc_k(const float* __restrict__ s0, const float* __restrict__ s1,
               short* __restrict__ d0, short* __restrict__ d1, int H, int W)
{
    const float* s = blockIdx.z ? s1 : s0;
    short* d = blockIdx.z ? d1 : d0;
    const int idx = blockIdx.x * BDIM + threadIdx.x;
    if (idx >= 4 * 32 * H * W) return;
    const int c = idx & 31;
    int t = idx >> 5;
    const int x = t % W; t /= W;
    const int y = t % H;
    const int b = t / H;
    d[idx] = (short)f2bf(s[(((size_t)b * 32 + c) * H + y) * W + x]);
}

// Bilinear 2x upsample, NHWC bf16, half-pixel centers, edge clamp.
__global__ __launch_bounds__(BDIM)
void up2b_k(const short* __restrict__ in, short* __restrict__ out,
            int Hin, int Win)
{
    const int Hout = 2 * Hin, Wout = 2 * Win;
    const int idx = blockIdx.x * BDIM + threadIdx.x;
    if (idx >= 4 * Hout * Wout * 4) return;
    const int cg = idx & 3;
    int t = idx >> 2;
    const int x = t % Wout; t /= Wout;
    const int y = t % Hout;
    const int b = t / Hout;

    const float sy = (y + 0.5f) * 0.5f - 0.5f;
    const float sx = (x + 0.5f) * 0.5f - 0.5f;
    const float y0f = floorf(sy), x0f = floorf(sx);
    const float wy = sy - y0f, wx = sx - x0f;
    const int y0 = (int)y0f, x0 = (int)x0f;
    const int y0c = min(max(y0, 0), Hin - 1);
    const int y1c = min(max(y0 + 1, 0), Hin - 1);
    const int x0c = min(max(x0, 0), Win - 1);
    const int x1c = min(max(x0 + 1, 0), Win - 1);

    const short* base = in + (size_t)b * Hin * Win * 32 + cg * 8;
    short8v v00 = *(const short8v*)(base + ((size_t)y0c * Win + x0c) * 32);
    short8v v01 = *(const short8v*)(base + ((size_t)y0c * Win + x1c) * 32);
    short8v v10 = *(const short8v*)(base + ((size_t)y1c * Win + x0c) * 32);
    short8v v11 = *(const short8v*)(base + ((size_t)y1c * Win + x1c) * 32);

    short8v o;
#pragma unroll
    for (int j = 0; j < 8; ++j) {
        float f = (1.f - wy) * ((1.f - wx) * bf2f((unsigned short)v00[j]) +
                                wx * bf2f((unsigned short)v01[j]))
                + wy * ((1.f - wx) * bf2f((unsigned short)v10[j]) +
                        wx * bf2f((unsigned short)v11[j]));
        o[j] = (short)f2bf(f);
    }
    short* op = out + (size_t)b * Hout * Wout * 32 + ((size_t)y * Wout + x) * 32 + cg * 8;
    *(short8v*)op = o;
}

// ---------------------------------------------------------------------------
// Fused conv_om + modulated deformable conv (DCNv2) on MFMA.
// Wave = 16 consecutive x-pixels. Phase 1: om = conv3x3(base_offset) on MFMA
// -> LDS [wave][pixel][112] (wave-private -> NO barrier). Phase 2: lane l =
// pixel (l&15), group (l>>4); bilinear sample + 2 MFMAs per tap.
__global__ __launch_bounds__(BDIM, 4)
void dcnm_k(const short* __restrict__ xb,    // fea2 NHWC bf16 [B][H][W][32]
            const short* __restrict__ bo,    // base_offset NHWC bf16
            const short* __restrict__ wfo,   // om A-frags [9][7][64][8]
            const float* __restrict__ obias, // om bias (108)
            const short* __restrict__ wfd,   // dcn A-frags [9][2][64][8]
            const float* __restrict__ bias,  // dcn bias (32)
            float* __restrict__ out, int H, int W)
{
    __shared__ unsigned short omld[4][16][112];   // 14336 B

    const int lane = threadIdx.x & 63;
    const int wv   = threadIdx.x >> 6;
    const int wid  = blockIdx.x * 4 + wv;
    const int segs = W >> 4;
    const int b = wid / (H * segs);
    int r = wid - b * (H * segs);
    const int y = r / segs;
    const int x0 = (r - y * segs) * 16;
    const int lp = lane & 15;
    const int g  = lane >> 4;
    const int x  = x0 + lp;
    const size_t plane = (size_t)H * W;
    const short8v zero = {};

    // ---------------- phase 1: om = conv_om(base_offset) ----------------
    {
        int rowOff[3]; bool rowOk[3];
#pragma unroll
        for (int ty = 0; ty < 3; ++ty) {
            const int iy = y + ty - 1;
            rowOk[ty] = (unsigned)iy < (unsigned)H;
            rowOff[ty] = min(max(iy, 0), H - 1) * W;
        }
        int colOff[3]; bool colOk[3];
#pragma unroll
        for (int tx = 0; tx < 3; ++tx) {
            const int ix = x + tx - 1;
            colOk[tx] = (unsigned)ix < (unsigned)W;
            colOff[tx] = min(max(ix, 0), W - 1) * 32 + g * 8;
        }
        const short* inp = bo + (size_t)b * plane * 32;
        short8v bv[9];
#pragma unroll
        for (int t = 0; t < 9; ++t) {
            const int ty = t / 3, tx = t % 3;
            short8v v = *(const short8v*)(inp + (size_t)rowOff[ty] * 32 + colOff[tx]);
            bv[t] = (rowOk[ty] & colOk[tx]) ? v : zero;
        }
        f32x4 acc[7];
#pragma unroll
        for (int h = 0; h < 7; ++h) acc[h] = (f32x4){0.f, 0.f, 0.f, 0.f};
#pragma unroll
        for (int t = 0; t < 9; ++t) {
#pragma unroll
            for (int h = 0; h < 7; ++h) {
                short8v av = *(const short8v*)(wfo + (((size_t)t * 7 + h) * 64 + lane) * 8);
                acc[h] = __builtin_amdgcn_mfma_f32_16x16x32_bf16(av, bv[t], acc[h], 0, 0, 0);
            }
        }
#pragma unroll
        for (int h = 0; h < 7; ++h) {
            const int co0 = h * 16 + g * 4;
            ushort4 st;
#pragma unroll
            for (int j = 0; j < 4; ++j)
                ((unsigned short*)&st)[j] = f2bf(acc[h][j] + obias[min(co0 + j, 107)]);
            *(ushort4*)&omld[wv][lp][co0] = st;
        }
    }
    // wave-private LDS: in-wave ds ordering + compiler lgkmcnt suffice

    // ---------------- phase 2: deformable sampling + PV ----------------
    f32x4 p0 = (f32x4){0.f, 0.f, 0.f, 0.f};
    f32x4 p1 = (f32x4){0.f, 0.f, 0.f, 0.f};
    const short* xbb = xb + (size_t)b * plane * 32 + g * 8;

#pragma unroll
    for (int k = 0; k < 9; ++k) {
        const float offy = bf2f(omld[wv][lp][g * 9 + k]);
        const float offx = bf2f(omld[wv][lp][36 + g * 9 + k]);
        const float ml   = bf2f(omld[wv][lp][72 + g * 9 + k]);
        const float m = 1.f / (1.f + __expf(-ml));

        const float py = offy + (float)y + (float)(k / 3 - 1);
        const float px = offx + (float)x + (float)(k % 3 - 1);
        const float y0f = floorf(py), x0f = floorf(px);
        const int y0 = (int)y0f, x0i = (int)x0f;
        const float wy1 = py - y0f, wx1 = px - x0f;
        const float wy0 = 1.f - wy1, wx0 = 1.f - wx1;

        const bool y0ok = (unsigned)y0 < (unsigned)H;
        const bool y1ok = (unsigned)(y0 + 1) < (unsigned)H;
        const bool x0ok = (unsigned)x0i < (unsigned)W;
        const bool x1ok = (unsigned)(x0i + 1) < (unsigned)W;
        const int y0c = min(max(y0, 0), H - 1);
        const int y1c = min(max(y0 + 1, 0), H - 1);
        const int x0c = min(max(x0i, 0), W - 1);
        const int x1c = min(max(x0i + 1, 0), W - 1);

        const float w00 = wy0 * wx0 * ((y0ok && x0ok) ? 1.f : 0.f) * m;
        const float w01 = wy0 * wx1 * ((y0ok && x1ok) ? 1.f : 0.f) * m;
        const float w10 = wy1 * wx0 * ((y1ok && x0ok) ? 1.f : 0.f) * m;
        const float w11 = wy1 * wx1 * ((y1ok && x1ok) ? 1.f : 0.f) * m;

        short8v v00 = *(const short8v*)(xbb + ((size_t)y0c * W + x0c) * 32);
        short8v v01 = *(const short8v*)(xbb + ((size_t)y0c * W + x1c) * 32);
        short8v v10 = *(const short8v*)(xbb + ((size_t)y1c * W + x0c) * 32);
        short8v v11 = *(const short8v*)(xbb + ((size_t)y1c * W + x1c) * 32);

        short8v bv;
#pragma unroll
        for (int j = 0; j < 8; ++j) {
            float s = w00 * bf2f((unsigned short)v00[j])
                    + w01 * bf2f((unsigned short)v01[j])
                    + w10 * bf2f((unsigned short)v10[j])
                    + w11 * bf2f((unsigned short)v11[j]);
            bv[j] = (short)f2bf(s);
        }

        short8v a0 = *(const short8v*)(wfd + (((size_t)k * 2 + 0) * 64 + lane) * 8);
        short8v a1 = *(const short8v*)(wfd + (((size_t)k * 2 + 1) * 64 + lane) * 8);
        p0 = __builtin_amdgcn_mfma_f32_16x16x32_bf16(a0, bv, p0, 0, 0, 0);
        p1 = __builtin_amdgcn_mfma_f32_16x16x32_bf16(a1, bv, p1, 0, 0, 0);
    }

    float* op = out + (size_t)b * 32 * plane + (size_t)y * W + x;
#pragma unroll
    for (int j = 0; j < 4; ++j) {
        const int co0 = g * 4 + j;
        const int co1 = 16 + g * 4 + j;
        op[(size_t)co0 * plane] = p0[j] + bias[co0];
        op[(size_t)co1 * plane] = p1[j] + bias[co1];
    }
}

// ---------------------------------------------------------------------------

extern "C" void kernel_launch(void* const* d_in, const int* in_sizes, int n_in,
                              void* d_out, int out_size, void* d_ws, size_t ws_size,
                              hipStream_t stream)
{
    const float* fea1  = (const float*)d_in[0];
    const float* fea2  = (const float*)d_in[1];
    const float* w1_1  = (const float*)d_in[2];  const float* b1_1 = (const float*)d_in[3];
    const float* w2_1  = (const float*)d_in[4];  const float* b2_1 = (const float*)d_in[5];
    const float* w3_1  = (const float*)d_in[6];  const float* b3_1 = (const float*)d_in[7];
    const float* w4_1  = (const float*)d_in[8];  const float* b4_1 = (const float*)d_in[9];
    const float* w6_1  = (const float*)d_in[10]; const float* b6_1 = (const float*)d_in[11];
    const float* w7_1  = (const float*)d_in[12]; const float* b7_1 = (const float*)d_in[13];
    const float* w1_2  = (const float*)d_in[14]; const float* b1_2 = (const float*)d_in[15];
    const float* w2_2  = (const float*)d_in[16]; const float* b2_2 = (const float*)d_in[17];
    const float* w3_2  = (const float*)d_in[18]; const float* b3_2 = (const float*)d_in[19];
    const float* w4_2  = (const float*)d_in[20]; const float* b4_2 = (const float*)d_in[21];
    const float* w_om  = (const float*)d_in[22]; const float* b_om = (const float*)d_in[23];
    const float* w_dcn = (const float*)d_in[24]; const float* b_dcn= (const float*)d_in[25];

    const int H = 192, W = 192;
    char* ws = (char*)d_ws;

    // byte offsets; fea2b stays live to the end (dcnm samples it)
    short* fea1b = (short*)(ws + 0);          // bf16 NHWC 192  (9.44 MB)
    short* fea2b = (short*)(ws + 9437184);    // LIVE TO END
    short* bufA  = (short*)(ws + 18874368);   // off      192
    short* bufB  = (short*)(ws + 28311552);   // off1     192 (lives to conv3_2)
    short* bufC  = (short*)(ws + 0);          // off2a    96  (fea1b dead)
    short* bufD  = (short*)(ws + 2359296);    // off2     96
    short* bufE  = (short*)(ws + 4718592);    // off3a    48
    short* bufF  = (short*)(ws + 5308416);    // off3     48
    short* bufG  = (short*)(ws + 5898240);    // up96     96
    short* bufH  = (short*)(ws + 0);          // conv1_2 out 96 (bufC dead)
    short* bufI  = (short*)(ws + 4718592);    // conv2_2 out 96 (E/F dead)
    short* bufJ  = (short*)(ws + 37748736);   // up192
    short* bufK  = (short*)(ws + 18874368);   // conv3_2 out (bufA dead)
    short* bufL  = (short*)(ws + 0);          // base_offset 192 (H/D/I dead)
    short* wfrag = (short*)(ws + 70778880);   // conv weight frags (304128 B)
    short* wfdcn = (short*)(ws + 71083008);   // dcn weight frags (18432 B)

    // fragment offsets in shorts per conv (om entry has nh=7 -> 32256 shorts)
    const int WOFF[11] = {0, 18432, 27648, 36864, 46080, 55296,
                          64512, 82944, 92160, 110592, 119808};

    dim3 blk(BDIM, 1, 1);

    // 0. weight prep + input conversions
    {
        WPArgs a;
        const float* srcs[11] = {w1_1, w2_1, w3_1, w4_1, w6_1, w7_1,
                                 w1_2, w2_2, w3_2, w4_2, w_om};
        const int NP[11] = {2,1,1,1,1,1,2,1,2,1,1};
        const int NH[11] = {2,2,2,2,2,2,2,2,2,2,7};
        const int Os[11] = {32,32,32,32,32,32,32,32,32,32,108};
        for (int i = 0; i < 11; ++i) {
            a.src[i] = srcs[i]; a.off[i] = WOFF[i];
            a.npass[i] = NP[i]; a.nhalf[i] = NH[i]; a.O[i] = Os[i];
        }
        wprep_k<<<dim3(126, 1, 11), blk, 0, stream>>>(a, wfrag);
        cvtnhwc_k<<<dim3(18432, 1, 2), blk, 0, stream>>>(fea1, fea2, fea1b, fea2b, H, W);
        wdp_k<<<dim3(36), blk, 0, stream>>>(w_dcn, wfdcn);
    }

    // 1. off = lrelu(conv1_1(cat(fea1, fea2)))           192  [rolling]
    convr_k<2,true,4><<<dim3(576), blk, 0, stream>>>(
        fea1b, fea2b, wfrag + WOFF[0], b1_1, bufA, 192, 192);
    // 2. off1 = lrelu(conv2_1(off))                      192  [rolling]
    convr_k<1,true,4><<<dim3(576), blk, 0, stream>>>(
        bufA, nullptr, wfrag + WOFF[1], b2_1, bufB, 192, 192);
    // 3. off2a = lrelu(conv3_1(off1, s2))                96
    convm_k<1,2,2,true><<<dim3(576), blk, 0, stream>>>(
        bufB, nullptr, wfrag + WOFF[2], b3_1, bufC, 192,192,96,96, 32);
    // 4. off2 = lrelu(conv4_1(off2a))                    96
    convm_k<1,2,1,true><<<dim3(576), blk, 0, stream>>>(
        bufC, nullptr, wfrag + WOFF[3], b4_1, bufD, 96,96,96,96, 32);
    // 5. off3a = lrelu(conv6_1(off2, s2))                48
    convm_k<1,2,2,true><<<dim3(144), blk, 0, stream>>>(
        bufD, nullptr, wfrag + WOFF[4], b6_1, bufE, 96,96,48,48, 32);
    // 6. off3 = lrelu(conv7_1(off3a))                    48
    convm_k<1,2,1,true><<<dim3(144), blk, 0, stream>>>(
        bufE, nullptr, wfrag + WOFF[5], b7_1, bufF, 48,48,48,48, 32);
    // 7. up96 = up2(off3)
    up2b_k<<<dim3(576), blk, 0, stream>>>(bufF, bufG, 48, 48);
    // 8. t = lrelu(conv1_2(cat(up96, off2)))             96
    convm_k<2,2,1,true><<<dim3(576), blk, 0, stream>>>(
        bufG, bufD, wfrag + WOFF[6], b1_2, bufH, 96,96,96,96, 32);
    // 9. t2 = lrelu(conv2_2(t))                          96
    convm_k<1,2,1,true><<<dim3(576), blk, 0, stream>>>(
        bufH, nullptr, wfrag + WOFF[7], b2_2, bufI, 96,96,96,96, 32);
    // 10. up192 = up2(t2)
    up2b_k<<<dim3(2304), blk, 0, stream>>>(bufI, bufJ, 96, 96);
    // 11. off = lrelu(conv3_2(cat(up192, off1)))         192  [rolling]
    convr_k<2,true,4><<<dim3(576), blk, 0, stream>>>(
        bufJ, bufB, wfrag + WOFF[8], b3_2, bufK, 192, 192);
    // 12. base_offset = conv4_2(off)    (no lrelu)       192  [rolling]
    convr_k<1,false,4><<<dim3(576), blk, 0, stream>>>(
        bufK, nullptr, wfrag + WOFF[9], b4_2, bufL, 192, 192);
    // 13. out = deform_conv(fea2, conv_om(base_offset))  [fused]
    dcnm_k<<<dim3(2304), blk, 0, stream>>>(
        fea2b, bufL, wfrag + WOFF[10], b_om, wfdcn, b_dcn, (float*)d_out, H, W);
}

// Round 9
// 311.175 us; speedup vs baseline: 1.0855x; 1.0068x over previous
//
#include <hip/hip_runtime.h>
#include <math.h>

// ---------------------------------------------------------------------------
// DCN_Align on MI355X. Convs AND deformable conv on MFMA bf16 (16x16x32).
// Big 192-res stride-1 convs: rolling-row sweep, YS=2, 4.5 blk/CU.
// DCN: conv_om fused; phase-2 gathers pipelined in 3 groups of 12
// independent loads (addresses+weights precomputed for all 9 taps).
// ---------------------------------------------------------------------------

#define BDIM 256

typedef __attribute__((ext_vector_type(8))) short short8v;
typedef __attribute__((ext_vector_type(4))) float f32x4;

__device__ __forceinline__ unsigned short f2bf(float f) {
    unsigned u = __builtin_bit_cast(unsigned, f);
    u = (u + 0x7FFF + ((u >> 16) & 1)) >> 16;   // round-to-nearest-even
    return (unsigned short)u;
}
__device__ __forceinline__ float bf2f(unsigned short h) {
    unsigned u = ((unsigned)h) << 16;
    return __builtin_bit_cast(float, u);
}

// ---------------------------------------------------------------------------
// Rolling-row MFMA conv, stride 1, Hin==Hout==H, 32 couts.
// Wave sweeps YS output rows of a 16-px column strip; 3-row B-window in
// registers, 3 new tap-loads per row per pass.
template<int NPASS, bool LRELU, int YS>
__global__ __launch_bounds__(BDIM, 3)
void convr_k(const short* __restrict__ in0, const short* __restrict__ in1,
             const short* __restrict__ wf,   // [pass][tap][2][lane][8] bf16
             const float* __restrict__ bias,
             short* __restrict__ out, int H, int W)
{
    const int lane = threadIdx.x & 63;
    const int wid  = blockIdx.x * 4 + (threadIdx.x >> 6);
    const int segs = W >> 4;
    const int strips = (H / YS) * segs;
    const int b = wid / strips;
    int r = wid - b * strips;
    const int ys = r / segs;
    const int y0 = ys * YS;
    const int x0 = (r - ys * segs) * 16;
    const int lp = lane & 15;
    const int g  = lane >> 4;

    int colOff[3]; bool colOk[3];
#pragma unroll
    for (int tx = 0; tx < 3; ++tx) {
        const int ix = x0 + lp + tx - 1;
        colOk[tx] = (unsigned)ix < (unsigned)W;
        colOff[tx] = min(max(ix, 0), W - 1) * 32 + g * 8;
    }

    const size_t inPlane = (size_t)H * W * 32;
    const short8v zero = {};
    const short* inp0 = in0 + (size_t)b * inPlane;
    const short* inp1 = (NPASS > 1) ? in1 + (size_t)b * inPlane : nullptr;

    short8v awc[(NPASS == 1) ? 18 : 1];
    if constexpr (NPASS == 1) {
#pragma unroll
        for (int t = 0; t < 9; ++t)
#pragma unroll
            for (int h = 0; h < 2; ++h)
                awc[t * 2 + h] = *(const short8v*)(
                    wf + (((size_t)t * 2 + h) * 64 + lane) * 8);
    }

    short8v win[NPASS][3][3];

#define LOADROW(SLOT, IY) do {                                                \
        const int iy_ = (IY);                                                 \
        const bool rok_ = (unsigned)iy_ < (unsigned)H;                        \
        const int ro_ = min(max(iy_, 0), H - 1) * W;                          \
        _Pragma("unroll")                                                     \
        for (int tx = 0; tx < 3; ++tx) {                                      \
            short8v v_ = *(const short8v*)(inp0 + (size_t)ro_ * 32 + colOff[tx]); \
            win[0][SLOT][tx] = (rok_ & colOk[tx]) ? v_ : zero;                \
            if constexpr (NPASS > 1) {                                        \
                short8v w_ = *(const short8v*)(inp1 + (size_t)ro_ * 32 + colOff[tx]); \
                win[1][SLOT][tx] = (rok_ & colOk[tx]) ? w_ : zero;            \
            }                                                                 \
        }                                                                     \
    } while (0)

    LOADROW(0, y0 - 1);
    LOADROW(1, y0);

#pragma unroll
    for (int s = 0; s < YS; ++s) {
        LOADROW((s + 2) % 3, y0 + s + 1);

        f32x4 a0 = (f32x4){0.f, 0.f, 0.f, 0.f};
        f32x4 a1 = (f32x4){0.f, 0.f, 0.f, 0.f};
#pragma unroll
        for (int p = 0; p < NPASS; ++p) {
#pragma unroll
            for (int ty = 0; ty < 3; ++ty) {
#pragma unroll
                for (int tx = 0; tx < 3; ++tx) {
                    const int t = ty * 3 + tx;
                    const short8v bv = win[p][(s + ty) % 3][tx];
                    short8v av0, av1;
                    if constexpr (NPASS == 1) {
                        av0 = awc[t * 2 + 0];
                        av1 = awc[t * 2 + 1];
                    } else {
                        av0 = *(const short8v*)(
                            wf + ((((size_t)p * 9 + t) * 2 + 0) * 64 + lane) * 8);
                        av1 = *(const short8v*)(
                            wf + ((((size_t)p * 9 + t) * 2 + 1) * 64 + lane) * 8);
                    }
                    a0 = __builtin_amdgcn_mfma_f32_16x16x32_bf16(av0, bv, a0, 0, 0, 0);
                    a1 = __builtin_amdgcn_mfma_f32_16x16x32_bf16(av1, bv, a1, 0, 0, 0);
                }
            }
        }

        short* op = out + (((size_t)b * H + (y0 + s)) * W + x0 + lp) * 32;
        ushort4 st0, st1;
#pragma unroll
        for (int j = 0; j < 4; ++j) {
            float v0 = a0[j] + bias[g * 4 + j];
            float v1 = a1[j] + bias[16 + g * 4 + j];
            if (LRELU) {
                v0 = (v0 >= 0.f) ? v0 : 0.1f * v0;
                v1 = (v1 >= 0.f) ? v1 : 0.1f * v1;
            }
            ((unsigned short*)&st0)[j] = f2bf(v0);
            ((unsigned short*)&st1)[j] = f2bf(v1);
        }
        *(ushort4*)(op + g * 4) = st0;
        *(ushort4*)(op + 16 + g * 4) = st1;
    }
#undef LOADROW
}

// ---------------------------------------------------------------------------
// Upfront-9-tap MFMA conv (small resolutions / strided).
template<int NPASS, int NHALF, int STRIDE, bool LRELU>
__global__ __launch_bounds__(BDIM, 4)
void convm_k(const short* __restrict__ in0, const short* __restrict__ in1,
             const short* __restrict__ wf,
             const float* __restrict__ bias,
             short* __restrict__ out,
             int Hin, int Win, int Hout, int Wout, int OCS)
{
    const int lane = threadIdx.x & 63;
    const int wid  = blockIdx.x * 4 + (threadIdx.x >> 6);
    const int segs = Wout >> 4;
    const int b  = wid / (Hout * segs);
    int r = wid - b * (Hout * segs);
    const int oy = r / segs;
    const int x0 = (r - oy * segs) * 16;
    const int lp = lane & 15;
    const int g  = lane >> 4;

    int rowOff[3]; bool rowOk[3];
#pragma unroll
    for (int ty = 0; ty < 3; ++ty) {
        const int iy = oy * STRIDE + ty - 1;
        rowOk[ty] = (unsigned)iy < (unsigned)Hin;
        rowOff[ty] = min(max(iy, 0), Hin - 1) * Win;
    }
    int colOff[3]; bool colOk[3];
#pragma unroll
    for (int tx = 0; tx < 3; ++tx) {
        const int ix = (x0 + lp) * STRIDE + tx - 1;
        colOk[tx] = (unsigned)ix < (unsigned)Win;
        colOff[tx] = min(max(ix, 0), Win - 1) * 32 + g * 8;
    }

    f32x4 acc[NHALF];
#pragma unroll
    for (int h = 0; h < NHALF; ++h) acc[h] = (f32x4){0.f, 0.f, 0.f, 0.f};

    const size_t inPlane = (size_t)Hin * Win * 32;
    const short8v zero = {};

#pragma unroll
    for (int pass = 0; pass < NPASS; ++pass) {
        const short* inp = (pass == 0 ? in0 : in1) + (size_t)b * inPlane;

        short8v bv[9];
#pragma unroll
        for (int t = 0; t < 9; ++t) {
            const int ty = t / 3, tx = t % 3;
            short8v v = *(const short8v*)(inp + (size_t)rowOff[ty] * 32 + colOff[tx]);
            bv[t] = (rowOk[ty] & colOk[tx]) ? v : zero;
        }
#pragma unroll
        for (int t = 0; t < 9; ++t) {
#pragma unroll
            for (int h = 0; h < NHALF; ++h) {
                short8v av = *(const short8v*)(
                    wf + ((((size_t)pass * 9 + t) * NHALF + h) * 64 + lane) * 8);
                acc[h] = __builtin_amdgcn_mfma_f32_16x16x32_bf16(av, bv[t], acc[h], 0, 0, 0);
            }
        }
    }

    short* op = out + (((size_t)b * Hout + oy) * Wout + x0 + lp) * OCS;
#pragma unroll
    for (int h = 0; h < NHALF; ++h) {
        const int co0 = h * 16 + g * 4;
        ushort4 st;
#pragma unroll
        for (int j = 0; j < 4; ++j) {
            float v = acc[h][j] + bias[co0 + j];
            if (LRELU) v = (v >= 0.f) ? v : 0.1f * v;
            ((unsigned short*)&st)[j] = f2bf(v);
        }
        *(ushort4*)(op + co0) = st;
    }
}

// ---------------------------------------------------------------------------
// Weight prep: [O][I][3][3] fp32 -> fragment layout bf16 [pass][t][h][lane][8].
struct WPArgs {
    const float* src[11];
    int off[11];      // dst offset in shorts
    int npass[11], nhalf[11], O[11];
};

__global__ __launch_bounds__(BDIM)
void wprep_k(WPArgs a, short* __restrict__ wbase)
{
    const int z = blockIdx.z;
    const int n = a.npass[z] * 9 * a.nhalf[z] * 512;
    const int idx = blockIdx.x * BDIM + threadIdx.x;
    if (idx >= n) return;
    const int j = idx & 7;
    const int l = (idx >> 3) & 63;
    int r = idx >> 9;
    const int h = r % a.nhalf[z]; r /= a.nhalf[z];
    const int t = r % 9;
    const int pass = r / 9;
    const int I = a.npass[z] * 32;
    const int cout = h * 16 + (l & 15);
    const int cin  = pass * 32 + (l >> 4) * 8 + j;
    float v = (cout < a.O[z]) ? a.src[z][((size_t)cout * I + cin) * 9 + t] : 0.f;
    wbase[a.off[z] + idx] = (short)f2bf(v);
}

// dcn weights [32o][32i][3][3] -> [tap][half][lane][8] bf16 frags
__global__ __launch_bounds__(BDIM)
void wdp_k(const float* __restrict__ w, short* __restrict__ dst)
{
    const int idx = blockIdx.x * BDIM + threadIdx.x;
    if (idx >= 9 * 2 * 64 * 8) return;
    const int j = idx & 7;
    const int l = (idx >> 3) & 63;
    const int h = (idx >> 9) & 1;
    const int k = idx >> 10;
    const int cout = h * 16 + (l & 15);
    const int cin  = (l >> 4) * 8 + j;
    dst[idx] = (short)f2bf(w[((size_t)cout * 32 + cin) * 9 + k]);
}

// fea NCHW fp32 -> NHWC bf16 (two tensors in one launch via z)
__global__ __launch_bounds__(BDIM)
void cvtnhwc_k(const float* __restrict__ s0, const float* __restrict__ s1,
               short* __restrict__ d0, short* __restrict__ d1, int H, int W)
{
    const float* s = blockIdx.z ? s1 : s0;
    short* d = blockIdx.z ? d1 : d0;
    const int idx = blockIdx.x * BDIM + threadIdx.x;
    if (idx >= 4 * 32 * H * W) return;
    const int c = idx & 31;
    int t = idx >> 5;
    const int x = t % W; t /= W;
    const int y = t % H;
    const int b = t / H;
    d[idx] = (short)f2bf(s[(((size_t)b * 32 + c) * H + y) * W + x]);
}

// Bilinear 2x upsample, NHWC bf16, half-pixel centers, edge clamp.
__global__ __launch_bounds__(BDIM)
void up2b_k(const short* __restrict__ in, short* __restrict__ out,
            int Hin, int Win)
{
    const int Hout = 2 * Hin, Wout = 2 * Win;
    const int idx = blockIdx.x * BDIM + threadIdx.x;
    if (idx >= 4 * Hout * Wout * 4) return;
    const int cg = idx & 3;
    int t = idx >> 2;
    const int x = t % Wout; t /= Wout;
    const int y = t % Hout;
    const int b = t / Hout;

    const float sy = (y + 0.5f) * 0.5f - 0.5f;
    const float sx = (x + 0.5f) * 0.5f - 0.5f;
    const float y0f = floorf(sy), x0f = floorf(sx);
    const float wy = sy - y0f, wx = sx - x0f;
    const int y0 = (int)y0f, x0 = (int)x0f;
    const int y0c = min(max(y0, 0), Hin - 1);
    const int y1c = min(max(y0 + 1, 0), Hin - 1);
    const int x0c = min(max(x0, 0), Win - 1);
    const int x1c = min(max(x0 + 1, 0), Win - 1);

    const short* base = in + (size_t)b * Hin * Win * 32 + cg * 8;
    short8v v00 = *(const short8v*)(base + ((size_t)y0c * Win + x0c) * 32);
    short8v v01 = *(const short8v*)(base + ((size_t)y0c * Win + x1c) * 32);
    short8v v10 = *(const short8v*)(base + ((size_t)y1c * Win + x0c) * 32);
    short8v v11 = *(const short8v*)(base + ((size_t)y1c * Win + x1c) * 32);

    short8v o;
#pragma unroll
    for (int j = 0; j < 8; ++j) {
        float f = (1.f - wy) * ((1.f - wx) * bf2f((unsigned short)v00[j]) +
                                wx * bf2f((unsigned short)v01[j]))
                + wy * ((1.f - wx) * bf2f((unsigned short)v10[j]) +
                        wx * bf2f((unsigned short)v11[j]));
        o[j] = (short)f2bf(f);
    }
    short* op = out + (size_t)b * Hout * Wout * 32 + ((size_t)y * Wout + x) * 32 + cg * 8;
    *(short8v*)op = o;
}

// ---------------------------------------------------------------------------
// Fused conv_om + modulated deformable conv (DCNv2) on MFMA.
// Phase 1: om = conv3x3(base_offset) on MFMA -> LDS [wave][16][116]
// (wave-private, padded stride -> ~conflict-free). Phase 2: precompute all
// 9 taps' folded weights + clamped indices, then 3 groups x 12 independent
// gather loads -> blend -> 2 MFMAs per tap.
__global__ __launch_bounds__(BDIM, 3)
void dcnm_k(const short* __restrict__ xb,    // fea2 NHWC bf16 [B][H][W][32]
            const short* __restrict__ bo,    // base_offset NHWC bf16
            const short* __restrict__ wfo,   // om A-frags [9][7][64][8]
            const float* __restrict__ obias, // om bias (108)
            const short* __restrict__ wfd,   // dcn A-frags [9][2][64][8]
            const float* __restrict__ bias,  // dcn bias (32)
            float* __restrict__ out, int H, int W)
{
    __shared__ unsigned short omld[4][16][116];   // padded stride: 58 dwords

    const int lane = threadIdx.x & 63;
    const int wv   = threadIdx.x >> 6;
    const int wid  = blockIdx.x * 4 + wv;
    const int segs = W >> 4;
    const int b = wid / (H * segs);
    int r = wid - b * (H * segs);
    const int y = r / segs;
    const int x0 = (r - y * segs) * 16;
    const int lp = lane & 15;
    const int g  = lane >> 4;
    const int x  = x0 + lp;
    const size_t plane = (size_t)H * W;
    const short8v zero = {};

    // ---------------- phase 1: om = conv_om(base_offset) ----------------
    {
        int rowOff[3]; bool rowOk[3];
#pragma unroll
        for (int ty = 0; ty < 3; ++ty) {
            const int iy = y + ty - 1;
            rowOk[ty] = (unsigned)iy < (unsigned)H;
            rowOff[ty] = min(max(iy, 0), H - 1) * W;
        }
        int colOff[3]; bool colOk[3];
#pragma unroll
        for (int tx = 0; tx < 3; ++tx) {
            const int ix = x + tx - 1;
            colOk[tx] = (unsigned)ix < (unsigned)W;
            colOff[tx] = min(max(ix, 0), W - 1) * 32 + g * 8;
        }
        const short* inp = bo + (size_t)b * plane * 32;
        short8v bv[9];
#pragma unroll
        for (int t = 0; t < 9; ++t) {
            const int ty = t / 3, tx = t % 3;
            short8v v = *(const short8v*)(inp + (size_t)rowOff[ty] * 32 + colOff[tx]);
            bv[t] = (rowOk[ty] & colOk[tx]) ? v : zero;
        }
        f32x4 acc[7];
#pragma unroll
        for (int h = 0; h < 7; ++h) acc[h] = (f32x4){0.f, 0.f, 0.f, 0.f};
#pragma unroll
        for (int t = 0; t < 9; ++t) {
#pragma unroll
            for (int h = 0; h < 7; ++h) {
                short8v av = *(const short8v*)(wfo + (((size_t)t * 7 + h) * 64 + lane) * 8);
                acc[h] = __builtin_amdgcn_mfma_f32_16x16x32_bf16(av, bv[t], acc[h], 0, 0, 0);
            }
        }
#pragma unroll
        for (int h = 0; h < 7; ++h) {
            const int co0 = h * 16 + g * 4;
            ushort4 st;
#pragma unroll
            for (int j = 0; j < 4; ++j)
                ((unsigned short*)&st)[j] = f2bf(acc[h][j] + obias[min(co0 + j, 107)]);
            *(ushort4*)&omld[wv][lp][co0] = st;
        }
    }
    // wave-private LDS: in-wave ds ordering + compiler lgkmcnt suffice

    // ---------------- phase 2: precompute, then pipelined gathers ----------
    float wts[9][4];
    int   ia[9][4];
#pragma unroll
    for (int k = 0; k < 9; ++k) {
        const float offy = bf2f(omld[wv][lp][g * 9 + k]);
        const float offx = bf2f(omld[wv][lp][36 + g * 9 + k]);
        const float ml   = bf2f(omld[wv][lp][72 + g * 9 + k]);
        const float m = 1.f / (1.f + __expf(-ml));

        const float py = offy + (float)y + (float)(k / 3 - 1);
        const float px = offx + (float)x + (float)(k % 3 - 1);
        const float y0f = floorf(py), x0f = floorf(px);
        const int y0 = (int)y0f, x0i = (int)x0f;
        const float wy1 = py - y0f, wx1 = px - x0f;
        const float wy0 = 1.f - wy1, wx0 = 1.f - wx1;

        const bool y0ok = (unsigned)y0 < (unsigned)H;
        const bool y1ok = (unsigned)(y0 + 1) < (unsigned)H;
        const bool x0ok = (unsigned)x0i < (unsigned)W;
        const bool x1ok = (unsigned)(x0i + 1) < (unsigned)W;
        const int y0c = min(max(y0, 0), H - 1);
        const int y1c = min(max(y0 + 1, 0), H - 1);
        const int x0c = min(max(x0i, 0), W - 1);
        const int x1c = min(max(x0i + 1, 0), W - 1);

        wts[k][0] = wy0 * wx0 * ((y0ok && x0ok) ? 1.f : 0.f) * m;
        wts[k][1] = wy0 * wx1 * ((y0ok && x1ok) ? 1.f : 0.f) * m;
        wts[k][2] = wy1 * wx0 * ((y1ok && x0ok) ? 1.f : 0.f) * m;
        wts[k][3] = wy1 * wx1 * ((y1ok && x1ok) ? 1.f : 0.f) * m;
        ia[k][0] = y0c * W + x0c;
        ia[k][1] = y0c * W + x1c;
        ia[k][2] = y1c * W + x0c;
        ia[k][3] = y1c * W + x1c;
    }

    f32x4 p0 = (f32x4){0.f, 0.f, 0.f, 0.f};
    f32x4 p1 = (f32x4){0.f, 0.f, 0.f, 0.f};
    const short* xbb = xb + (size_t)b * plane * 32 + g * 8;

#pragma unroll
    for (int gi = 0; gi < 3; ++gi) {
        short8v cd[12];
#pragma unroll
        for (int t = 0; t < 3; ++t) {
            const int k = gi * 3 + t;
#pragma unroll
            for (int c = 0; c < 4; ++c)
                cd[t * 4 + c] = *(const short8v*)(xbb + (size_t)ia[k][c] * 32);
        }
#pragma unroll
        for (int t = 0; t < 3; ++t) {
            const int k = gi * 3 + t;
            short8v bv;
#pragma unroll
            for (int j = 0; j < 8; ++j) {
                float s = wts[k][0] * bf2f((unsigned short)cd[t * 4 + 0][j])
                        + wts[k][1] * bf2f((unsigned short)cd[t * 4 + 1][j])
                        + wts[k][2] * bf2f((unsigned short)cd[t * 4 + 2][j])
                        + wts[k][3] * bf2f((unsigned short)cd[t * 4 + 3][j]);
                bv[j] = (short)f2bf(s);
            }
            short8v a0 = *(const short8v*)(wfd + (((size_t)k * 2 + 0) * 64 + lane) * 8);
            short8v a1 = *(const short8v*)(wfd + (((size_t)k * 2 + 1) * 64 + lane) * 8);
            p0 = __builtin_amdgcn_mfma_f32_16x16x32_bf16(a0, bv, p0, 0, 0, 0);
            p1 = __builtin_amdgcn_mfma_f32_16x16x32_bf16(a1, bv, p1, 0, 0, 0);
        }
    }

    float* op = out + (size_t)b * 32 * plane + (size_t)y * W + x;
#pragma unroll
    for (int j = 0; j < 4; ++j) {
        const int co0 = g * 4 + j;
        const int co1 = 16 + g * 4 + j;
        op[(size_t)co0 * plane] = p0[j] + bias[co0];
        op[(size_t)co1 * plane] = p1[j] + bias[co1];
    }
}

// ---------------------------------------------------------------------------

extern "C" void kernel_launch(void* const* d_in, const int* in_sizes, int n_in,
                              void* d_out, int out_size, void* d_ws, size_t ws_size,
                              hipStream_t stream)
{
    const float* fea1  = (const float*)d_in[0];
    const float* fea2  = (const float*)d_in[1];
    const float* w1_1  = (const float*)d_in[2];  const float* b1_1 = (const float*)d_in[3];
    const float* w2_1  = (const float*)d_in[4];  const float* b2_1 = (const float*)d_in[5];
    const float* w3_1  = (const float*)d_in[6];  const float* b3_1 = (const float*)d_in[7];
    const float* w4_1  = (const float*)d_in[8];  const float* b4_1 = (const float*)d_in[9];
    const float* w6_1  = (const float*)d_in[10]; const float* b6_1 = (const float*)d_in[11];
    const float* w7_1  = (const float*)d_in[12]; const float* b7_1 = (const float*)d_in[13];
    const float* w1_2  = (const float*)d_in[14]; const float* b1_2 = (const float*)d_in[15];
    const float* w2_2  = (const float*)d_in[16]; const float* b2_2 = (const float*)d_in[17];
    const float* w3_2  = (const float*)d_in[18]; const float* b3_2 = (const float*)d_in[19];
    const float* w4_2  = (const float*)d_in[20]; const float* b4_2 = (const float*)d_in[21];
    const float* w_om  = (const float*)d_in[22]; const float* b_om = (const float*)d_in[23];
    const float* w_dcn = (const float*)d_in[24]; const float* b_dcn= (const float*)d_in[25];

    const int H = 192, W = 192;
    char* ws = (char*)d_ws;

    // byte offsets; fea2b stays live to the end (dcnm samples it)
    short* fea1b = (short*)(ws + 0);          // bf16 NHWC 192  (9.44 MB)
    short* fea2b = (short*)(ws + 9437184);    // LIVE TO END
    short* bufA  = (short*)(ws + 18874368);   // off      192
    short* bufB  = (short*)(ws + 28311552);   // off1     192 (lives to conv3_2)
    short* bufC  = (short*)(ws + 0);          // off2a    96  (fea1b dead)
    short* bufD  = (short*)(ws + 2359296);    // off2     96
    short* bufE  = (short*)(ws + 4718592);    // off3a    48
    short* bufF  = (short*)(ws + 5308416);    // off3     48
    short* bufG  = (short*)(ws + 5898240);    // up96     96
    short* bufH  = (short*)(ws + 0);          // conv1_2 out 96 (bufC dead)
    short* bufI  = (short*)(ws + 4718592);    // conv2_2 out 96 (E/F dead)
    short* bufJ  = (short*)(ws + 37748736);   // up192
    short* bufK  = (short*)(ws + 18874368);   // conv3_2 out (bufA dead)
    short* bufL  = (short*)(ws + 0);          // base_offset 192 (H/D/I dead)
    short* wfrag = (short*)(ws + 70778880);   // conv weight frags (304128 B)
    short* wfdcn = (short*)(ws + 71083008);   // dcn weight frags (18432 B)

    // fragment offsets in shorts per conv (om entry has nh=7 -> 32256 shorts)
    const int WOFF[11] = {0, 18432, 27648, 36864, 46080, 55296,
                          64512, 82944, 92160, 110592, 119808};

    dim3 blk(BDIM, 1, 1);

    // 0. weight prep + input conversions
    {
        WPArgs a;
        const float* srcs[11] = {w1_1, w2_1, w3_1, w4_1, w6_1, w7_1,
                                 w1_2, w2_2, w3_2, w4_2, w_om};
        const int NP[11] = {2,1,1,1,1,1,2,1,2,1,1};
        const int NH[11] = {2,2,2,2,2,2,2,2,2,2,7};
        const int Os[11] = {32,32,32,32,32,32,32,32,32,32,108};
        for (int i = 0; i < 11; ++i) {
            a.src[i] = srcs[i]; a.off[i] = WOFF[i];
            a.npass[i] = NP[i]; a.nhalf[i] = NH[i]; a.O[i] = Os[i];
        }
        wprep_k<<<dim3(126, 1, 11), blk, 0, stream>>>(a, wfrag);
        cvtnhwc_k<<<dim3(18432, 1, 2), blk, 0, stream>>>(fea1, fea2, fea1b, fea2b, H, W);
        wdp_k<<<dim3(36), blk, 0, stream>>>(w_dcn, wfdcn);
    }

    // 1. off = lrelu(conv1_1(cat(fea1, fea2)))           192  [rolling YS=2]
    convr_k<2,true,2><<<dim3(1152), blk, 0, stream>>>(
        fea1b, fea2b, wfrag + WOFF[0], b1_1, bufA, 192, 192);
    // 2. off1 = lrelu(conv2_1(off))                      192  [rolling YS=2]
    convr_k<1,true,2><<<dim3(1152), blk, 0, stream>>>(
        bufA, nullptr, wfrag + WOFF[1], b2_1, bufB, 192, 192);
    // 3. off2a = lrelu(conv3_1(off1, s2))                96
    convm_k<1,2,2,true><<<dim3(576), blk, 0, stream>>>(
        bufB, nullptr, wfrag + WOFF[2], b3_1, bufC, 192,192,96,96, 32);
    // 4. off2 = lrelu(conv4_1(off2a))                    96
    convm_k<1,2,1,true><<<dim3(576), blk, 0, stream>>>(
        bufC, nullptr, wfrag + WOFF[3], b4_1, bufD, 96,96,96,96, 32);
    // 5. off3a = lrelu(conv6_1(off2, s2))                48
    convm_k<1,2,2,true><<<dim3(144), blk, 0, stream>>>(
        bufD, nullptr, wfrag + WOFF[4], b6_1, bufE, 96,96,48,48, 32);
    // 6. off3 = lrelu(conv7_1(off3a))                    48
    convm_k<1,2,1,true><<<dim3(144), blk, 0, stream>>>(
        bufE, nullptr, wfrag + WOFF[5], b7_1, bufF, 48,48,48,48, 32);
    // 7. up96 = up2(off3)
    up2b_k<<<dim3(576), blk, 0, stream>>>(bufF, bufG, 48, 48);
    // 8. t = lrelu(conv1_2(cat(up96, off2)))             96
    convm_k<2,2,1,true><<<dim3(576), blk, 0, stream>>>(
        bufG, bufD, wfrag + WOFF[6], b1_2, bufH, 96,96,96,96, 32);
    // 9. t2 = lrelu(conv2_2(t))                          96
    convm_k<1,2,1,true><<<dim3(576), blk, 0, stream>>>(
        bufH, nullptr, wfrag + WOFF[7], b2_2, bufI, 96,96,96,96, 32);
    // 10. up192 = up2(t2)
    up2b_k<<<dim3(2304), blk, 0, stream>>>(bufI, bufJ, 96, 96);
    // 11. off = lrelu(conv3_2(cat(up192, off1)))         192  [rolling YS=2]
    convr_k<2,true,2><<<dim3(1152), blk, 0, stream>>>(
        bufJ, bufB, wfrag + WOFF[8], b3_2, bufK, 192, 192);
    // 12. base_offset = conv4_2(off)    (no lrelu)       192  [rolling YS=2]
    convr_k<1,false,2><<<dim3(1152), blk, 0, stream>>>(
        bufK, nullptr, wfrag + WOFF[9], b4_2, bufL, 192, 192);
    // 13. out = deform_conv(fea2, conv_om(base_offset))  [fused]
    dcnm_k<<<dim3(2304), blk, 0, stream>>>(
        fea2b, bufL, wfrag + WOFF[10], b_om, wfdcn, b_dcn, (float*)d_out, H, W);
}